// Round 2
// baseline (1382.821 us; speedup 1.0000x reference)
//
#include <hip/hip_runtime.h>
#include <hip/hip_fp16.h>

typedef _Float16 v8h __attribute__((ext_vector_type(8)));
typedef float v4f __attribute__((ext_vector_type(4)));

#define T_DIM 512
#define B_DIM 256
#define F_DIM 258
#define IN_DIM 256
#define H_DIM 1024
#define M_ROWS (T_DIM * B_DIM) /* 131072 */

// ---------------------------------------------------------------------------
// prep (per chunk): u_chunk (Mc, 258) fp32 -> X_chunk (Mc, 256) fp16 + c1 seg
// ---------------------------------------------------------------------------
__global__ void prep_u_kernel(const float* __restrict__ u,
                              _Float16* __restrict__ X,
                              float* __restrict__ c1, int n) {
    int i = blockIdx.x * blockDim.x + threadIdx.x;
    int stride = gridDim.x * blockDim.x;
    for (; i < n; i += stride) {
        float v = u[i];
        unsigned r = (unsigned)i / 258u;
        unsigned c = (unsigned)i - r * 258u;
        if (c >= 2u) {
            X[r * 256u + (c - 2u)] = (_Float16)v;
        } else if (c == 1u) {
            c1[r] = v;
        }
    }
}

// ---------------------------------------------------------------------------
// weight convert + transpose: W (K x N) fp32 -> Wt (N x K) fp16
// ---------------------------------------------------------------------------
__global__ void wt_kernel(const float* __restrict__ W, _Float16* __restrict__ Wt,
                          int K, int N, int total) {
    int i = blockIdx.x * blockDim.x + threadIdx.x;
    int stride = gridDim.x * blockDim.x;
    for (; i < total; i += stride) {
        int k = i / N;
        int n = i - k * N;
        Wt[(size_t)n * K + k] = (_Float16)W[i];
    }
}

// ---------------------------------------------------------------------------
// GEMM: C[M,N] = relu(A[M,K] @ Bt[N,K]^T + bias[N])
// 128x128 tile, BK=32, 256 threads (4 waves, each 64x64 via 4x4 mfma tiles)
// ---------------------------------------------------------------------------
__global__ __launch_bounds__(256)
void gemm_f16(const _Float16* __restrict__ A, const _Float16* __restrict__ Bt,
              const float* __restrict__ bias, _Float16* __restrict__ C,
              int M, int N, int K, int do_relu) {
    __shared__ _Float16 sA[128 * 32];
    __shared__ _Float16 sB[128 * 32];

    const int tid = threadIdx.x;
    const int lane = tid & 63;
    const int wave = tid >> 6;
    const int wm = wave >> 1;       // 0..1
    const int wn = wave & 1;        // 0..1
    const int quad = lane >> 4;     // 0..3
    const int r16 = lane & 15;      // 0..15

    const int m0 = blockIdx.x * 128;
    const int n0 = blockIdx.y * 128;

    // staging: each thread moves 4 x 16B (2 for A, 2 for B)
    const int sr = tid >> 2;          // 0..63
    const int sc = (tid & 3) * 8;     // 0,8,16,24

    v4f acc[4][4];
#pragma unroll
    for (int i = 0; i < 4; ++i)
#pragma unroll
        for (int j = 0; j < 4; ++j) acc[i][j] = (v4f)0.f;

    v8h ra0, ra1, rb0, rb1;
    auto load_tile = [&](int k0) {
        ra0 = *(const v8h*)&A[(size_t)(m0 + sr) * K + k0 + sc];
        ra1 = *(const v8h*)&A[(size_t)(m0 + sr + 64) * K + k0 + sc];
        rb0 = *(const v8h*)&Bt[(size_t)(n0 + sr) * K + k0 + sc];
        rb1 = *(const v8h*)&Bt[(size_t)(n0 + sr + 64) * K + k0 + sc];
    };

    load_tile(0);
    for (int k0 = 0; k0 < K; k0 += 32) {
        __syncthreads();
        *(v8h*)&sA[sr * 32 + sc] = ra0;
        *(v8h*)&sA[(sr + 64) * 32 + sc] = ra1;
        *(v8h*)&sB[sr * 32 + sc] = rb0;
        *(v8h*)&sB[(sr + 64) * 32 + sc] = rb1;
        __syncthreads();
        if (k0 + 32 < K) load_tile(k0 + 32);

        v8h af[4], bf[4];
#pragma unroll
        for (int i = 0; i < 4; ++i)
            af[i] = *(const v8h*)&sA[(wm * 64 + i * 16 + r16) * 32 + quad * 8];
#pragma unroll
        for (int i = 0; i < 4; ++i)
            bf[i] = *(const v8h*)&sB[(wn * 64 + i * 16 + r16) * 32 + quad * 8];
#pragma unroll
        for (int mi = 0; mi < 4; ++mi)
#pragma unroll
            for (int ni = 0; ni < 4; ++ni)
                acc[mi][ni] = __builtin_amdgcn_mfma_f32_16x16x32_f16(
                    af[mi], bf[ni], acc[mi][ni], 0, 0, 0);
    }

    // epilogue: C/D layout col = lane&15, row = (lane>>4)*4 + reg
    float bv[4];
#pragma unroll
    for (int ni = 0; ni < 4; ++ni) bv[ni] = bias[n0 + wn * 64 + ni * 16 + r16];

#pragma unroll
    for (int mi = 0; mi < 4; ++mi) {
#pragma unroll
        for (int ni = 0; ni < 4; ++ni) {
#pragma unroll
            for (int i = 0; i < 4; ++i) {
                int row = m0 + wm * 64 + mi * 16 + quad * 4 + i;
                int col = n0 + wn * 64 + ni * 16 + r16;
                float v = acc[mi][ni][i] + bv[ni];
                if (do_relu) v = fmaxf(v, 0.f);
                C[(size_t)row * N + col] = (_Float16)v;
            }
        }
    }
}

// ---------------------------------------------------------------------------
// layer 4: net[m] = H[m,:] . w3 + b3   (one wave per row)
// ---------------------------------------------------------------------------
__global__ void dot3_kernel(const _Float16* __restrict__ H,
                            const _Float16* __restrict__ w3,
                            const float* __restrict__ b3,
                            float* __restrict__ net, int M) {
    int row = (blockIdx.x * blockDim.x + threadIdx.x) >> 6;
    int lane = threadIdx.x & 63;
    if (row >= M) return;
    const _Float16* hr = H + (size_t)row * H_DIM;
    float s = 0.f;
#pragma unroll
    for (int c = 0; c < 2; ++c) {
        v8h hv = *(const v8h*)&hr[c * 512 + lane * 8];
        v8h wv = *(const v8h*)&w3[c * 512 + lane * 8];
#pragma unroll
        for (int j = 0; j < 8; ++j) s += (float)hv[j] * (float)wv[j];
    }
#pragma unroll
    for (int off = 32; off > 0; off >>= 1) s += __shfl_down(s, off);
    if (lane == 0) net[row] = s + b3[0];
}

// ---------------------------------------------------------------------------
// scan: y_t = a*y_{t-1} + b*c1_t + net_t ; out = [y0; ys]  (one block, 256 lanes)
// ---------------------------------------------------------------------------
__global__ void scan_kernel(const float* __restrict__ net,
                            const float* __restrict__ c1,
                            const float* __restrict__ u,
                            const float* __restrict__ pa,
                            const float* __restrict__ pb,
                            float* __restrict__ out) {
    const int bidx = threadIdx.x;  // 0..255
    const float a = pa[0];
    const float b = pb[0];
    float y = u[(size_t)bidx * F_DIM];  // u[0, b, 0]
    out[bidx] = y;
#pragma unroll 8
    for (int t = 0; t < T_DIM; ++t) {
        float z = fmaf(b, c1[t * B_DIM + bidx], net[t * B_DIM + bidx]);
        y = fmaf(a, y, z);
        out[(t + 1) * B_DIM + bidx] = y;
    }
}

// ---------------------------------------------------------------------------
extern "C" void kernel_launch(void* const* d_in, const int* in_sizes, int n_in,
                              void* d_out, int out_size, void* d_ws, size_t ws_size,
                              hipStream_t stream) {
    const float* u = (const float*)d_in[0];
    const float* pa = (const float*)d_in[1];
    const float* pb = (const float*)d_in[2];
    const float* W0 = (const float*)d_in[3];
    const float* b0 = (const float*)d_in[4];
    const float* W1 = (const float*)d_in[5];
    const float* b1 = (const float*)d_in[6];
    const float* W2 = (const float*)d_in[7];
    const float* b2 = (const float*)d_in[8];
    const float* W3 = (const float*)d_in[9];
    const float* b3 = (const float*)d_in[10];
    float* out = (float*)d_out;

    char* ws = (char*)d_ws;
    size_t off = 0;
    auto alloc = [&](size_t bytes) -> void* {
        void* p = ws + off;
        off += (bytes + 255) & ~(size_t)255;
        return p;
    };

    // ---- fixed residents (~5.8 MB) ----
    float* net = (float*)alloc((size_t)M_ROWS * 4);
    float* c1 = (float*)alloc((size_t)M_ROWS * 4);
    _Float16* W0T = (_Float16*)alloc((size_t)IN_DIM * H_DIM * 2);
    _Float16* W1T = (_Float16*)alloc((size_t)H_DIM * H_DIM * 2);
    _Float16* W2T = (_Float16*)alloc((size_t)H_DIM * H_DIM * 2);
    _Float16* W3h = (_Float16*)alloc((size_t)H_DIM * 2);

    // ---- chunk size: fit X(512B/row) + HA(2KB/row) + HB(2KB/row) in what's left ----
    const size_t per_row = 512 + 2048 + 2048; // 4608 B
    size_t avail = (ws_size > off + 65536) ? (ws_size - off - 65536) : 0;
    long Rl = (long)(avail / per_row);
    Rl = (Rl / 128) * 128;
    if (Rl < 128) Rl = 128;               // minimum viable; below this nothing fits
    if (Rl > M_ROWS) Rl = M_ROWS;
    const int R = (int)Rl;

    _Float16* Xc = (_Float16*)alloc((size_t)R * IN_DIM * 2);
    _Float16* HAc = (_Float16*)alloc((size_t)R * H_DIM * 2);
    _Float16* HBc = (_Float16*)alloc((size_t)R * H_DIM * 2);

    // ---- weights once ----
    wt_kernel<<<256, 256, 0, stream>>>(W0, W0T, IN_DIM, H_DIM, IN_DIM * H_DIM);
    wt_kernel<<<512, 256, 0, stream>>>(W1, W1T, H_DIM, H_DIM, H_DIM * H_DIM);
    wt_kernel<<<512, 256, 0, stream>>>(W2, W2T, H_DIM, H_DIM, H_DIM * H_DIM);
    wt_kernel<<<4, 256, 0, stream>>>(W3, W3h, H_DIM, 1, H_DIM);

    // ---- chunked MLP pipeline ----
    for (int r0 = 0; r0 < M_ROWS; r0 += R) {
        int Mc = M_ROWS - r0;
        if (Mc > R) Mc = R;
        int nElem = Mc * F_DIM;
        int pgrid = (nElem + 256 * 8 - 1) / (256 * 8);
        if (pgrid > 2048) pgrid = 2048;
        prep_u_kernel<<<pgrid, 256, 0, stream>>>(u + (size_t)r0 * F_DIM, Xc,
                                                 c1 + r0, nElem);

        dim3 blk(256);
        dim3 grd(Mc / 128, H_DIM / 128);
        gemm_f16<<<grd, blk, 0, stream>>>(Xc, W0T, b0, HAc, Mc, H_DIM, IN_DIM, 1);
        gemm_f16<<<grd, blk, 0, stream>>>(HAc, W1T, b1, HBc, Mc, H_DIM, H_DIM, 1);
        gemm_f16<<<grd, blk, 0, stream>>>(HBc, W2T, b2, HAc, Mc, H_DIM, H_DIM, 1);

        dot3_kernel<<<Mc / 4, 256, 0, stream>>>(HAc, W3h, b3, net + r0, Mc);
    }

    // ---- scan ----
    scan_kernel<<<1, 256, 0, stream>>>(net, c1, u, pa, pb, out);
}

// Round 3
// 1329.823 us; speedup vs baseline: 1.0399x; 1.0399x over previous
//
#include <hip/hip_runtime.h>
#include <hip/hip_fp16.h>

typedef _Float16 v8h __attribute__((ext_vector_type(8)));
typedef float v4f __attribute__((ext_vector_type(4)));

#define T_DIM 512
#define B_DIM 256
#define F_DIM 258
#define IN_DIM 256
#define H_DIM 1024
#define M_ROWS (T_DIM * B_DIM) /* 131072 */

// async global->LDS, 16B per lane; lds dest = wave-uniform base + lane*16
__device__ __forceinline__ void async_copy16(const void* g, void* l) {
    __builtin_amdgcn_global_load_lds(
        (const __attribute__((address_space(1))) void*)g,
        (__attribute__((address_space(3))) void*)l, 16, 0, 0);
}

// ---------------------------------------------------------------------------
// prep (per chunk): u_chunk (Mc, 258) fp32 -> X_chunk (Mc, 256) fp16 + c1 seg
// ---------------------------------------------------------------------------
__global__ void prep_u_kernel(const float* __restrict__ u,
                              _Float16* __restrict__ X,
                              float* __restrict__ c1, int n) {
    int i = blockIdx.x * blockDim.x + threadIdx.x;
    int stride = gridDim.x * blockDim.x;
    for (; i < n; i += stride) {
        float v = u[i];
        unsigned r = (unsigned)i / 258u;
        unsigned c = (unsigned)i - r * 258u;
        if (c >= 2u) {
            X[r * 256u + (c - 2u)] = (_Float16)v;
        } else if (c == 1u) {
            c1[r] = v;
        }
    }
}

// ---------------------------------------------------------------------------
// weight convert + transpose: W (K x N) fp32 -> Wt (N x K) fp16
// ---------------------------------------------------------------------------
__global__ void wt_kernel(const float* __restrict__ W, _Float16* __restrict__ Wt,
                          int K, int N, int total) {
    int i = blockIdx.x * blockDim.x + threadIdx.x;
    int stride = gridDim.x * blockDim.x;
    for (; i < total; i += stride) {
        int k = i / N;
        int n = i - k * N;
        Wt[(size_t)n * K + k] = (_Float16)W[i];
    }
}

__global__ void zero_kernel(float* __restrict__ p, int n) {
    int i = blockIdx.x * blockDim.x + threadIdx.x;
    if (i < n) p[i] = 0.f;
}

// ---------------------------------------------------------------------------
// GEMM: C[M,N] = relu(A[M,K] @ Bt[N,K]^T + bias[N])
// 128x128 tile, BK=32, 256 threads, global_load_lds(16B) staging (m97-style)
// grid: x = n-tile, y = m-tile (consecutive blocks share the A tile)
// ---------------------------------------------------------------------------
__global__ __launch_bounds__(256)
void gemm_f16(const _Float16* __restrict__ A, const _Float16* __restrict__ Bt,
              const float* __restrict__ bias, _Float16* __restrict__ C,
              int M, int N, int K) {
    __shared__ _Float16 sA[128 * 32];
    __shared__ _Float16 sB[128 * 32];

    const int tid = threadIdx.x;
    const int lane = tid & 63;
    const int wave = tid >> 6;
    const int wm = wave >> 1;
    const int wn = wave & 1;
    const int quad = lane >> 4;
    const int r16 = lane & 15;

    const int n0 = blockIdx.x * 128;
    const int m0 = blockIdx.y * 128;

    // staging: wave w stages rows [w*32, w*32+32) via two 16-row instructions
    const int srow = (lane >> 2);        // 0..15
    const int scol = (lane & 3) * 8;     // halves
    const _Float16* gA0 = A + (size_t)(m0 + wave * 32 + srow) * K + scol;
    const _Float16* gA1 = gA0 + (size_t)16 * K;
    const _Float16* gB0 = Bt + (size_t)(n0 + wave * 32 + srow) * K + scol;
    const _Float16* gB1 = gB0 + (size_t)16 * K;
    _Float16* lA0 = &sA[(wave * 32) * 32];        // wave-uniform LDS bases
    _Float16* lA1 = &sA[(wave * 32 + 16) * 32];
    _Float16* lB0 = &sB[(wave * 32) * 32];
    _Float16* lB1 = &sB[(wave * 32 + 16) * 32];

    v4f acc[4][4];
#pragma unroll
    for (int i = 0; i < 4; ++i)
#pragma unroll
        for (int j = 0; j < 4; ++j) acc[i][j] = (v4f)0.f;

    for (int k0 = 0; k0 < K; k0 += 32) {
        async_copy16(gA0 + k0, lA0);
        async_copy16(gA1 + k0, lA1);
        async_copy16(gB0 + k0, lB0);
        async_copy16(gB1 + k0, lB1);
        __syncthreads();   // drains vmcnt(0): LDS tiles ready

        v8h af[4], bf[4];
#pragma unroll
        for (int i = 0; i < 4; ++i)
            af[i] = *(const v8h*)&sA[(wm * 64 + i * 16 + r16) * 32 + quad * 8];
#pragma unroll
        for (int i = 0; i < 4; ++i)
            bf[i] = *(const v8h*)&sB[(wn * 64 + i * 16 + r16) * 32 + quad * 8];
#pragma unroll
        for (int mi = 0; mi < 4; ++mi)
#pragma unroll
            for (int ni = 0; ni < 4; ++ni)
                acc[mi][ni] = __builtin_amdgcn_mfma_f32_16x16x32_f16(
                    af[mi], bf[ni], acc[mi][ni], 0, 0, 0);
        __syncthreads();   // all waves done reading before next overwrite
    }

    float bv[4];
#pragma unroll
    for (int ni = 0; ni < 4; ++ni) bv[ni] = bias[n0 + wn * 64 + ni * 16 + r16];

#pragma unroll
    for (int mi = 0; mi < 4; ++mi) {
#pragma unroll
        for (int ni = 0; ni < 4; ++ni) {
#pragma unroll
            for (int i = 0; i < 4; ++i) {
                int row = m0 + wm * 64 + mi * 16 + quad * 4 + i;
                int col = n0 + wn * 64 + ni * 16 + r16;
                float v = fmaxf(acc[mi][ni][i] + bv[ni], 0.f);
                C[(size_t)row * N + col] = (_Float16)v;
            }
        }
    }
}

// ---------------------------------------------------------------------------
// Final GEMM fused with layer-4 dot: net[m] += sum_n relu(A@W2^T+b2)[m,n]*w3[n]
// Same body; epilogue reduces across the tile's 128 columns and atomicAdds.
// ---------------------------------------------------------------------------
__global__ __launch_bounds__(256)
void gemm_dot(const _Float16* __restrict__ A, const _Float16* __restrict__ Bt,
              const float* __restrict__ bias, const _Float16* __restrict__ w3,
              float* __restrict__ net, int M, int N, int K) {
    __shared__ _Float16 sA[128 * 32];
    __shared__ _Float16 sB[128 * 32];

    const int tid = threadIdx.x;
    const int lane = tid & 63;
    const int wave = tid >> 6;
    const int wm = wave >> 1;
    const int wn = wave & 1;
    const int quad = lane >> 4;
    const int r16 = lane & 15;

    const int n0 = blockIdx.x * 128;
    const int m0 = blockIdx.y * 128;

    const int srow = (lane >> 2);
    const int scol = (lane & 3) * 8;
    const _Float16* gA0 = A + (size_t)(m0 + wave * 32 + srow) * K + scol;
    const _Float16* gA1 = gA0 + (size_t)16 * K;
    const _Float16* gB0 = Bt + (size_t)(n0 + wave * 32 + srow) * K + scol;
    const _Float16* gB1 = gB0 + (size_t)16 * K;
    _Float16* lA0 = &sA[(wave * 32) * 32];
    _Float16* lA1 = &sA[(wave * 32 + 16) * 32];
    _Float16* lB0 = &sB[(wave * 32) * 32];
    _Float16* lB1 = &sB[(wave * 32 + 16) * 32];

    v4f acc[4][4];
#pragma unroll
    for (int i = 0; i < 4; ++i)
#pragma unroll
        for (int j = 0; j < 4; ++j) acc[i][j] = (v4f)0.f;

    for (int k0 = 0; k0 < K; k0 += 32) {
        async_copy16(gA0 + k0, lA0);
        async_copy16(gA1 + k0, lA1);
        async_copy16(gB0 + k0, lB0);
        async_copy16(gB1 + k0, lB1);
        __syncthreads();

        v8h af[4], bf[4];
#pragma unroll
        for (int i = 0; i < 4; ++i)
            af[i] = *(const v8h*)&sA[(wm * 64 + i * 16 + r16) * 32 + quad * 8];
#pragma unroll
        for (int i = 0; i < 4; ++i)
            bf[i] = *(const v8h*)&sB[(wn * 64 + i * 16 + r16) * 32 + quad * 8];
#pragma unroll
        for (int mi = 0; mi < 4; ++mi)
#pragma unroll
            for (int ni = 0; ni < 4; ++ni)
                acc[mi][ni] = __builtin_amdgcn_mfma_f32_16x16x32_f16(
                    af[mi], bf[ni], acc[mi][ni], 0, 0, 0);
        __syncthreads();
    }

    float bv[4], w3v[4];
#pragma unroll
    for (int ni = 0; ni < 4; ++ni) {
        int col = n0 + wn * 64 + ni * 16 + r16;
        bv[ni] = bias[col];
        w3v[ni] = (float)w3[col];
    }

#pragma unroll
    for (int mi = 0; mi < 4; ++mi) {
#pragma unroll
        for (int i = 0; i < 4; ++i) {
            float t = 0.f;
#pragma unroll
            for (int ni = 0; ni < 4; ++ni) {
                float v = fmaxf(acc[mi][ni][i] + bv[ni], 0.f);
                t = fmaf(v, w3v[ni], t);
            }
            // reduce across the 16 lanes of this quad (r16 = 0..15)
#pragma unroll
            for (int off = 1; off < 16; off <<= 1) t += __shfl_xor(t, off);
            if (r16 == 0) {
                int row = m0 + wm * 64 + mi * 16 + quad * 4 + i;
                atomicAdd(&net[row], t);
            }
        }
    }
}

// ---------------------------------------------------------------------------
// scan: y_t = a*y_{t-1} + b*c1_t + (net_t + b3) ; out = [y0; ys]
// ---------------------------------------------------------------------------
__global__ void scan_kernel(const float* __restrict__ net,
                            const float* __restrict__ c1,
                            const float* __restrict__ u,
                            const float* __restrict__ pa,
                            const float* __restrict__ pb,
                            const float* __restrict__ pb3,
                            float* __restrict__ out) {
    const int bidx = threadIdx.x;  // 0..255
    const float a = pa[0];
    const float b = pb[0];
    const float b3 = pb3[0];
    float y = u[(size_t)bidx * F_DIM];  // u[0, b, 0]
    out[bidx] = y;
#pragma unroll 8
    for (int t = 0; t < T_DIM; ++t) {
        float z = fmaf(b, c1[t * B_DIM + bidx], net[t * B_DIM + bidx] + b3);
        y = fmaf(a, y, z);
        out[(t + 1) * B_DIM + bidx] = y;
    }
}

// ---------------------------------------------------------------------------
extern "C" void kernel_launch(void* const* d_in, const int* in_sizes, int n_in,
                              void* d_out, int out_size, void* d_ws, size_t ws_size,
                              hipStream_t stream) {
    const float* u = (const float*)d_in[0];
    const float* pa = (const float*)d_in[1];
    const float* pb = (const float*)d_in[2];
    const float* W0 = (const float*)d_in[3];
    const float* b0 = (const float*)d_in[4];
    const float* W1 = (const float*)d_in[5];
    const float* b1 = (const float*)d_in[6];
    const float* W2 = (const float*)d_in[7];
    const float* b2 = (const float*)d_in[8];
    const float* W3 = (const float*)d_in[9];
    const float* b3 = (const float*)d_in[10];
    float* out = (float*)d_out;

    char* ws = (char*)d_ws;
    size_t off = 0;
    auto alloc = [&](size_t bytes) -> void* {
        void* p = ws + off;
        off += (bytes + 255) & ~(size_t)255;
        return p;
    };

    // ---- fixed residents (~5.8 MB) ----
    float* net = (float*)alloc((size_t)M_ROWS * 4);
    float* c1 = (float*)alloc((size_t)M_ROWS * 4);
    _Float16* W0T = (_Float16*)alloc((size_t)IN_DIM * H_DIM * 2);
    _Float16* W1T = (_Float16*)alloc((size_t)H_DIM * H_DIM * 2);
    _Float16* W2T = (_Float16*)alloc((size_t)H_DIM * H_DIM * 2);
    _Float16* W3h = (_Float16*)alloc((size_t)H_DIM * 2);

    // ---- chunk size: X(512B/row) + HA(2KB/row) + HB(2KB/row) ----
    const size_t per_row = 512 + 2048 + 2048;
    size_t avail = (ws_size > off + 65536) ? (ws_size - off - 65536) : 0;
    long Rl = (long)(avail / per_row);
    Rl = (Rl / 128) * 128;
    if (Rl < 128) Rl = 128;
    if (Rl > M_ROWS) Rl = M_ROWS;
    const int R = (int)Rl;

    _Float16* Xc = (_Float16*)alloc((size_t)R * IN_DIM * 2);
    _Float16* HAc = (_Float16*)alloc((size_t)R * H_DIM * 2);
    _Float16* HBc = (_Float16*)alloc((size_t)R * H_DIM * 2);

    // ---- weights once per call ----
    wt_kernel<<<256, 256, 0, stream>>>(W0, W0T, IN_DIM, H_DIM, IN_DIM * H_DIM);
    wt_kernel<<<512, 256, 0, stream>>>(W1, W1T, H_DIM, H_DIM, H_DIM * H_DIM);
    wt_kernel<<<512, 256, 0, stream>>>(W2, W2T, H_DIM, H_DIM, H_DIM * H_DIM);
    wt_kernel<<<4, 256, 0, stream>>>(W3, W3h, H_DIM, 1, H_DIM);
    zero_kernel<<<M_ROWS / 256, 256, 0, stream>>>(net, M_ROWS);

    // ---- chunked MLP pipeline ----
    for (int r0 = 0; r0 < M_ROWS; r0 += R) {
        int Mc = M_ROWS - r0;
        if (Mc > R) Mc = R;
        int nElem = Mc * F_DIM;
        int pgrid = (nElem + 256 * 8 - 1) / (256 * 8);
        if (pgrid > 2048) pgrid = 2048;
        prep_u_kernel<<<pgrid, 256, 0, stream>>>(u + (size_t)r0 * F_DIM, Xc,
                                                 c1 + r0, nElem);

        dim3 blk(256);
        dim3 grd(H_DIM / 128, Mc / 128);  // x = n-tile, y = m-tile
        gemm_f16<<<grd, blk, 0, stream>>>(Xc, W0T, b0, HAc, Mc, H_DIM, IN_DIM);
        gemm_f16<<<grd, blk, 0, stream>>>(HAc, W1T, b1, HBc, Mc, H_DIM, H_DIM);
        gemm_dot<<<grd, blk, 0, stream>>>(HBc, W2T, b2, W3h, net + r0, Mc,
                                          H_DIM, H_DIM);
    }

    // ---- scan ----
    scan_kernel<<<1, 256, 0, stream>>>(net, c1, u, pa, pb, b3, out);
}

// Round 4
// 1246.723 us; speedup vs baseline: 1.1092x; 1.0667x over previous
//
#include <hip/hip_runtime.h>
#include <hip/hip_fp16.h>

typedef _Float16 v8h __attribute__((ext_vector_type(8)));
typedef float v4f __attribute__((ext_vector_type(4)));

#define T_DIM 512
#define B_DIM 256
#define F_DIM 258
#define IN_DIM 256
#define H_DIM 1024
#define M_ROWS (T_DIM * B_DIM) /* 131072 */

// async global->LDS, 16B per lane; lds dest = wave-uniform base + lane*16
__device__ __forceinline__ void async_copy16(const void* g, void* l) {
    __builtin_amdgcn_global_load_lds(
        (const __attribute__((address_space(1))) void*)g,
        (__attribute__((address_space(3))) void*)l, 16, 0, 0);
}

// XCD-aware tile map: round-robin dispatch puts block b on XCD b%8. Give each
// XCD a contiguous m-range with n fastest, so the 8 n-blocks sharing one
// A-tile are consecutive ON THE SAME XCD -> A-tile fetched once into its L2.
__device__ __forceinline__ void tile_map(int b, int nM, int nN, int& mt, int& nt) {
    if (((nM & 7) == 0) && (nN == 8)) {
        int xcd = b & 7;
        int l = b >> 3;          // sequence within this XCD
        int mpx = nM >> 3;       // m-tiles per XCD
        mt = xcd * mpx + (l >> 3);
        nt = l & 7;
    } else {                     // fallback: plain n-fastest
        mt = b / nN;
        nt = b - mt * nN;
    }
}

// ---------------------------------------------------------------------------
// prep (per chunk): u_chunk (Mc, 258) fp32 -> X_chunk (Mc, 256) fp16 + c1 seg
// ---------------------------------------------------------------------------
__global__ void prep_u_kernel(const float* __restrict__ u,
                              _Float16* __restrict__ X,
                              float* __restrict__ c1, int n) {
    int i = blockIdx.x * blockDim.x + threadIdx.x;
    int stride = gridDim.x * blockDim.x;
    for (; i < n; i += stride) {
        float v = u[i];
        unsigned r = (unsigned)i / 258u;
        unsigned c = (unsigned)i - r * 258u;
        if (c >= 2u) {
            X[r * 256u + (c - 2u)] = (_Float16)v;
        } else if (c == 1u) {
            c1[r] = v;
        }
    }
}

// ---------------------------------------------------------------------------
// weight convert + transpose: W (K x N) fp32 -> Wt (N x K) fp16
// ---------------------------------------------------------------------------
__global__ void wt_kernel(const float* __restrict__ W, _Float16* __restrict__ Wt,
                          int K, int N, int total) {
    int i = blockIdx.x * blockDim.x + threadIdx.x;
    int stride = gridDim.x * blockDim.x;
    for (; i < total; i += stride) {
        int k = i / N;
        int n = i - k * N;
        Wt[(size_t)n * K + k] = (_Float16)W[i];
    }
}

__global__ void zero_kernel(float* __restrict__ p, int n) {
    int i = blockIdx.x * blockDim.x + threadIdx.x;
    if (i < n) p[i] = 0.f;
}

// ---------------------------------------------------------------------------
// GEMM: C[M,N] = relu(A[M,K] @ Bt[N,K]^T + bias[N])
// 128x128 tile, BK=32, 256 threads, global_load_lds(16B), XCD-swizzled grid
// ---------------------------------------------------------------------------
__global__ __launch_bounds__(256)
void gemm_f16(const _Float16* __restrict__ A, const _Float16* __restrict__ Bt,
              const float* __restrict__ bias, _Float16* __restrict__ C,
              int M, int N, int K) {
    __shared__ _Float16 sA[128 * 32];
    __shared__ _Float16 sB[128 * 32];

    const int tid = threadIdx.x;
    const int lane = tid & 63;
    const int wave = tid >> 6;
    const int wm = wave >> 1;
    const int wn = wave & 1;
    const int quad = lane >> 4;
    const int r16 = lane & 15;

    int mt, nt;
    tile_map(blockIdx.x, M >> 7, N >> 7, mt, nt);
    const int m0 = mt * 128;
    const int n0 = nt * 128;

    const int srow = (lane >> 2);        // 0..15
    const int scol = (lane & 3) * 8;
    const _Float16* gA0 = A + (size_t)(m0 + wave * 32 + srow) * K + scol;
    const _Float16* gA1 = gA0 + (size_t)16 * K;
    const _Float16* gB0 = Bt + (size_t)(n0 + wave * 32 + srow) * K + scol;
    const _Float16* gB1 = gB0 + (size_t)16 * K;
    _Float16* lA0 = &sA[(wave * 32) * 32];
    _Float16* lA1 = &sA[(wave * 32 + 16) * 32];
    _Float16* lB0 = &sB[(wave * 32) * 32];
    _Float16* lB1 = &sB[(wave * 32 + 16) * 32];

    v4f acc[4][4];
#pragma unroll
    for (int i = 0; i < 4; ++i)
#pragma unroll
        for (int j = 0; j < 4; ++j) acc[i][j] = (v4f)0.f;

    for (int k0 = 0; k0 < K; k0 += 32) {
        async_copy16(gA0 + k0, lA0);
        async_copy16(gA1 + k0, lA1);
        async_copy16(gB0 + k0, lB0);
        async_copy16(gB1 + k0, lB1);
        __syncthreads();

        v8h af[4], bf[4];
#pragma unroll
        for (int i = 0; i < 4; ++i)
            af[i] = *(const v8h*)&sA[(wm * 64 + i * 16 + r16) * 32 + quad * 8];
#pragma unroll
        for (int i = 0; i < 4; ++i)
            bf[i] = *(const v8h*)&sB[(wn * 64 + i * 16 + r16) * 32 + quad * 8];
#pragma unroll
        for (int mi = 0; mi < 4; ++mi)
#pragma unroll
            for (int ni = 0; ni < 4; ++ni)
                acc[mi][ni] = __builtin_amdgcn_mfma_f32_16x16x32_f16(
                    af[mi], bf[ni], acc[mi][ni], 0, 0, 0);
        __syncthreads();
    }

    float bv[4];
#pragma unroll
    for (int ni = 0; ni < 4; ++ni) bv[ni] = bias[n0 + wn * 64 + ni * 16 + r16];

#pragma unroll
    for (int mi = 0; mi < 4; ++mi) {
#pragma unroll
        for (int ni = 0; ni < 4; ++ni) {
#pragma unroll
            for (int i = 0; i < 4; ++i) {
                int row = m0 + wm * 64 + mi * 16 + quad * 4 + i;
                int col = n0 + wn * 64 + ni * 16 + r16;
                float v = fmaxf(acc[mi][ni][i] + bv[ni], 0.f);
                C[(size_t)row * N + col] = (_Float16)v;
            }
        }
    }
}

// ---------------------------------------------------------------------------
// Final GEMM fused with layer-4 dot: net[m] += sum_n relu(A@W2^T+b2)[m,n]*w3[n]
// ---------------------------------------------------------------------------
__global__ __launch_bounds__(256)
void gemm_dot(const _Float16* __restrict__ A, const _Float16* __restrict__ Bt,
              const float* __restrict__ bias, const _Float16* __restrict__ w3,
              float* __restrict__ net, int M, int N, int K) {
    __shared__ _Float16 sA[128 * 32];
    __shared__ _Float16 sB[128 * 32];

    const int tid = threadIdx.x;
    const int lane = tid & 63;
    const int wave = tid >> 6;
    const int wm = wave >> 1;
    const int wn = wave & 1;
    const int quad = lane >> 4;
    const int r16 = lane & 15;

    int mt, nt;
    tile_map(blockIdx.x, M >> 7, N >> 7, mt, nt);
    const int m0 = mt * 128;
    const int n0 = nt * 128;

    const int srow = (lane >> 2);
    const int scol = (lane & 3) * 8;
    const _Float16* gA0 = A + (size_t)(m0 + wave * 32 + srow) * K + scol;
    const _Float16* gA1 = gA0 + (size_t)16 * K;
    const _Float16* gB0 = Bt + (size_t)(n0 + wave * 32 + srow) * K + scol;
    const _Float16* gB1 = gB0 + (size_t)16 * K;
    _Float16* lA0 = &sA[(wave * 32) * 32];
    _Float16* lA1 = &sA[(wave * 32 + 16) * 32];
    _Float16* lB0 = &sB[(wave * 32) * 32];
    _Float16* lB1 = &sB[(wave * 32 + 16) * 32];

    v4f acc[4][4];
#pragma unroll
    for (int i = 0; i < 4; ++i)
#pragma unroll
        for (int j = 0; j < 4; ++j) acc[i][j] = (v4f)0.f;

    for (int k0 = 0; k0 < K; k0 += 32) {
        async_copy16(gA0 + k0, lA0);
        async_copy16(gA1 + k0, lA1);
        async_copy16(gB0 + k0, lB0);
        async_copy16(gB1 + k0, lB1);
        __syncthreads();

        v8h af[4], bf[4];
#pragma unroll
        for (int i = 0; i < 4; ++i)
            af[i] = *(const v8h*)&sA[(wm * 64 + i * 16 + r16) * 32 + quad * 8];
#pragma unroll
        for (int i = 0; i < 4; ++i)
            bf[i] = *(const v8h*)&sB[(wn * 64 + i * 16 + r16) * 32 + quad * 8];
#pragma unroll
        for (int mi = 0; mi < 4; ++mi)
#pragma unroll
            for (int ni = 0; ni < 4; ++ni)
                acc[mi][ni] = __builtin_amdgcn_mfma_f32_16x16x32_f16(
                    af[mi], bf[ni], acc[mi][ni], 0, 0, 0);
        __syncthreads();
    }

    float bv[4], w3v[4];
#pragma unroll
    for (int ni = 0; ni < 4; ++ni) {
        int col = n0 + wn * 64 + ni * 16 + r16;
        bv[ni] = bias[col];
        w3v[ni] = (float)w3[col];
    }

#pragma unroll
    for (int mi = 0; mi < 4; ++mi) {
#pragma unroll
        for (int i = 0; i < 4; ++i) {
            float t = 0.f;
#pragma unroll
            for (int ni = 0; ni < 4; ++ni) {
                float v = fmaxf(acc[mi][ni][i] + bv[ni], 0.f);
                t = fmaf(v, w3v[ni], t);
            }
#pragma unroll
            for (int off = 1; off < 16; off <<= 1) t += __shfl_xor(t, off);
            if (r16 == 0) {
                int row = m0 + wm * 64 + mi * 16 + quad * 4 + i;
                atomicAdd(&net[row], t);
            }
        }
    }
}

// ---------------------------------------------------------------------------
// scan: y_t = a*y_{t-1} + b*c1_t + (net_t + b3) ; out = [y0; ys]
// ---------------------------------------------------------------------------
__global__ void scan_kernel(const float* __restrict__ net,
                            const float* __restrict__ c1,
                            const float* __restrict__ u,
                            const float* __restrict__ pa,
                            const float* __restrict__ pb,
                            const float* __restrict__ pb3,
                            float* __restrict__ out) {
    const int bidx = threadIdx.x;  // 0..255
    const float a = pa[0];
    const float b = pb[0];
    const float b3 = pb3[0];
    float y = u[(size_t)bidx * F_DIM];  // u[0, b, 0]
    out[bidx] = y;
#pragma unroll 8
    for (int t = 0; t < T_DIM; ++t) {
        float z = fmaf(b, c1[t * B_DIM + bidx], net[t * B_DIM + bidx] + b3);
        y = fmaf(a, y, z);
        out[(t + 1) * B_DIM + bidx] = y;
    }
}

// ---------------------------------------------------------------------------
extern "C" void kernel_launch(void* const* d_in, const int* in_sizes, int n_in,
                              void* d_out, int out_size, void* d_ws, size_t ws_size,
                              hipStream_t stream) {
    const float* u = (const float*)d_in[0];
    const float* pa = (const float*)d_in[1];
    const float* pb = (const float*)d_in[2];
    const float* W0 = (const float*)d_in[3];
    const float* b0 = (const float*)d_in[4];
    const float* W1 = (const float*)d_in[5];
    const float* b1 = (const float*)d_in[6];
    const float* W2 = (const float*)d_in[7];
    const float* b2 = (const float*)d_in[8];
    const float* W3 = (const float*)d_in[9];
    const float* b3 = (const float*)d_in[10];
    float* out = (float*)d_out;

    char* ws = (char*)d_ws;
    size_t off = 0;
    auto alloc = [&](size_t bytes) -> void* {
        void* p = ws + off;
        off += (bytes + 255) & ~(size_t)255;
        return p;
    };

    // ---- fixed residents (~5.8 MB) ----
    float* net = (float*)alloc((size_t)M_ROWS * 4);
    float* c1 = (float*)alloc((size_t)M_ROWS * 4);
    _Float16* W0T = (_Float16*)alloc((size_t)IN_DIM * H_DIM * 2);
    _Float16* W1T = (_Float16*)alloc((size_t)H_DIM * H_DIM * 2);
    _Float16* W2T = (_Float16*)alloc((size_t)H_DIM * H_DIM * 2);
    _Float16* W3h = (_Float16*)alloc((size_t)H_DIM * 2);

    // ---- chunk rows: multiple of 1024 so m-tiles per chunk are divisible
    //      by 8 (keeps the XCD swizzle path); X+HA+HB = 4608 B/row ----
    const size_t per_row = 512 + 2048 + 2048;
    size_t avail = (ws_size > off + 65536) ? (ws_size - off - 65536) : 0;
    long Rl = (long)(avail / per_row);
    Rl = (Rl / 1024) * 1024;
    if (Rl < 128) Rl = 128;  // last-resort tiny chunk (fallback tile map)
    if (Rl > M_ROWS) Rl = M_ROWS;
    const int R = (int)Rl;

    _Float16* Xc = (_Float16*)alloc((size_t)R * IN_DIM * 2);
    _Float16* HAc = (_Float16*)alloc((size_t)R * H_DIM * 2);
    _Float16* HBc = (_Float16*)alloc((size_t)R * H_DIM * 2);

    // ---- weights once per call ----
    wt_kernel<<<256, 256, 0, stream>>>(W0, W0T, IN_DIM, H_DIM, IN_DIM * H_DIM);
    wt_kernel<<<512, 256, 0, stream>>>(W1, W1T, H_DIM, H_DIM, H_DIM * H_DIM);
    wt_kernel<<<512, 256, 0, stream>>>(W2, W2T, H_DIM, H_DIM, H_DIM * H_DIM);
    wt_kernel<<<4, 256, 0, stream>>>(W3, W3h, H_DIM, 1, H_DIM);
    zero_kernel<<<M_ROWS / 256, 256, 0, stream>>>(net, M_ROWS);

    // ---- chunked MLP pipeline ----
    for (int r0 = 0; r0 < M_ROWS; r0 += R) {
        int Mc = M_ROWS - r0;
        if (Mc > R) Mc = R;
        int nElem = Mc * F_DIM;
        int pgrid = (nElem + 256 * 8 - 1) / (256 * 8);
        if (pgrid > 2048) pgrid = 2048;
        prep_u_kernel<<<pgrid, 256, 0, stream>>>(u + (size_t)r0 * F_DIM, Xc,
                                                 c1 + r0, nElem);

        dim3 blk(256);
        dim3 grd((Mc / 128) * (H_DIM / 128));  // 1D, swizzled in-kernel
        gemm_f16<<<grd, blk, 0, stream>>>(Xc, W0T, b0, HAc, Mc, H_DIM, IN_DIM);
        gemm_f16<<<grd, blk, 0, stream>>>(HAc, W1T, b1, HBc, Mc, H_DIM, H_DIM);
        gemm_dot<<<grd, blk, 0, stream>>>(HBc, W2T, b2, W3h, net + r0, Mc,
                                          H_DIM, H_DIM);
    }

    // ---- scan ----
    scan_kernel<<<1, 256, 0, stream>>>(net, c1, u, pa, pb, b3, out);
}

// Round 5
// 1178.556 us; speedup vs baseline: 1.1733x; 1.0578x over previous
//
#include <hip/hip_runtime.h>
#include <hip/hip_fp16.h>

typedef _Float16 v8h __attribute__((ext_vector_type(8)));
typedef float v4f __attribute__((ext_vector_type(4)));

#define T_DIM 512
#define B_DIM 256
#define F_DIM 258
#define IN_DIM 256
#define H_DIM 1024
#define M_ROWS (T_DIM * B_DIM) /* 131072 */

// async global->LDS, 16B per lane; lds dest = wave-uniform base + lane*16
__device__ __forceinline__ void async_copy16(const void* g, void* l) {
    __builtin_amdgcn_global_load_lds(
        (const __attribute__((address_space(1))) void*)g,
        (__attribute__((address_space(3))) void*)l, 16, 0, 0);
}

// XCD-aware tile map: round-robin dispatch puts block b on XCD b%8. Give each
// XCD a contiguous m-range with n fastest, so the 8 n-blocks sharing one
// A-tile are consecutive ON THE SAME XCD -> A-tile fetched once into its L2.
// [R4: FETCH_SIZE 939->185 MB — keep]
__device__ __forceinline__ void tile_map(int b, int nM, int nN, int& mt, int& nt) {
    if (((nM & 7) == 0) && (nN == 8)) {
        int xcd = b & 7;
        int l = b >> 3;          // sequence within this XCD
        int mpx = nM >> 3;       // m-tiles per XCD
        mt = xcd * mpx + (l >> 3);
        nt = l & 7;
    } else {                     // fallback: plain n-fastest
        mt = b / nN;
        nt = b - mt * nN;
    }
}

// ---------------------------------------------------------------------------
// prep (per chunk): u_chunk (Mc, 258) fp32 -> X_chunk (Mc, 256) fp16 + c1 seg
// ---------------------------------------------------------------------------
__global__ void prep_u_kernel(const float* __restrict__ u,
                              _Float16* __restrict__ X,
                              float* __restrict__ c1, int n) {
    int i = blockIdx.x * blockDim.x + threadIdx.x;
    int stride = gridDim.x * blockDim.x;
    for (; i < n; i += stride) {
        float v = u[i];
        unsigned r = (unsigned)i / 258u;
        unsigned c = (unsigned)i - r * 258u;
        if (c >= 2u) {
            X[r * 256u + (c - 2u)] = (_Float16)v;
        } else if (c == 1u) {
            c1[r] = v;
        }
    }
}

// ---------------------------------------------------------------------------
// weight convert + transpose: W (K x N) fp32 -> Wt (N x K) fp16
// ---------------------------------------------------------------------------
__global__ void wt_kernel(const float* __restrict__ W, _Float16* __restrict__ Wt,
                          int K, int N, int total) {
    int i = blockIdx.x * blockDim.x + threadIdx.x;
    int stride = gridDim.x * blockDim.x;
    for (; i < total; i += stride) {
        int k = i / N;
        int n = i - k * N;
        Wt[(size_t)n * K + k] = (_Float16)W[i];
    }
}

__global__ void zero_kernel(float* __restrict__ p, int n) {
    int i = blockIdx.x * blockDim.x + threadIdx.x;
    if (i < n) p[i] = 0.f;
}

// ---------------------------------------------------------------------------
// GEMM: C[M,N] = relu(A[M,K] @ Bt[N,K]^T + bias[N])
// 128x128 tile, BK=32, 256 threads, global_load_lds(16B), XCD-swizzled grid.
// R5: double-buffered LDS, prefetch tile k+1 AFTER the barrier that publishes
// tile k, ONE barrier per iter -> drain overlaps the compute window.
// ---------------------------------------------------------------------------
__global__ __launch_bounds__(256)
void gemm_f16(const _Float16* __restrict__ A, const _Float16* __restrict__ Bt,
              const float* __restrict__ bias, _Float16* __restrict__ C,
              int M, int N, int K) {
    __shared__ _Float16 sA[2][128 * 32];
    __shared__ _Float16 sB[2][128 * 32];

    const int tid = threadIdx.x;
    const int lane = tid & 63;
    const int wave = tid >> 6;
    const int wm = wave >> 1;
    const int wn = wave & 1;
    const int quad = lane >> 4;
    const int r16 = lane & 15;

    int mt, nt;
    tile_map(blockIdx.x, M >> 7, N >> 7, mt, nt);
    const int m0 = mt * 128;
    const int n0 = nt * 128;

    const int srow = (lane >> 2);        // 0..15
    const int scol = (lane & 3) * 8;
    const _Float16* gA0 = A + (size_t)(m0 + wave * 32 + srow) * K + scol;
    const _Float16* gA1 = gA0 + (size_t)16 * K;
    const _Float16* gB0 = Bt + (size_t)(n0 + wave * 32 + srow) * K + scol;
    const _Float16* gB1 = gB0 + (size_t)16 * K;
    const int ldsOff0 = (wave * 32) * 32;        // wave-uniform LDS offsets
    const int ldsOff1 = (wave * 32 + 16) * 32;

    v4f acc[4][4];
#pragma unroll
    for (int i = 0; i < 4; ++i)
#pragma unroll
        for (int j = 0; j < 4; ++j) acc[i][j] = (v4f)0.f;

    const int NT = K >> 5;
    // prologue: tile 0 -> buf 0
    async_copy16(gA0, &sA[0][ldsOff0]);
    async_copy16(gA1, &sA[0][ldsOff1]);
    async_copy16(gB0, &sB[0][ldsOff0]);
    async_copy16(gB1, &sB[0][ldsOff1]);

    for (int kt = 0; kt < NT; ++kt) {
        const int cur = kt & 1;
        __syncthreads();               // publishes tile kt in buf cur
        if (kt + 1 < NT) {             // prefetch kt+1 into the free buffer
            const int k0 = (kt + 1) << 5;
            async_copy16(gA0 + k0, &sA[cur ^ 1][ldsOff0]);
            async_copy16(gA1 + k0, &sA[cur ^ 1][ldsOff1]);
            async_copy16(gB0 + k0, &sB[cur ^ 1][ldsOff0]);
            async_copy16(gB1 + k0, &sB[cur ^ 1][ldsOff1]);
        }

        v8h af[4], bf[4];
#pragma unroll
        for (int i = 0; i < 4; ++i)
            af[i] = *(const v8h*)&sA[cur][(wm * 64 + i * 16 + r16) * 32 + quad * 8];
#pragma unroll
        for (int i = 0; i < 4; ++i)
            bf[i] = *(const v8h*)&sB[cur][(wn * 64 + i * 16 + r16) * 32 + quad * 8];
#pragma unroll
        for (int mi = 0; mi < 4; ++mi)
#pragma unroll
            for (int ni = 0; ni < 4; ++ni)
                acc[mi][ni] = __builtin_amdgcn_mfma_f32_16x16x32_f16(
                    af[mi], bf[ni], acc[mi][ni], 0, 0, 0);
    }

    float bv[4];
#pragma unroll
    for (int ni = 0; ni < 4; ++ni) bv[ni] = bias[n0 + wn * 64 + ni * 16 + r16];

#pragma unroll
    for (int mi = 0; mi < 4; ++mi) {
#pragma unroll
        for (int ni = 0; ni < 4; ++ni) {
#pragma unroll
            for (int i = 0; i < 4; ++i) {
                int row = m0 + wm * 64 + mi * 16 + quad * 4 + i;
                int col = n0 + wn * 64 + ni * 16 + r16;
                float v = fmaxf(acc[mi][ni][i] + bv[ni], 0.f);
                C[(size_t)row * N + col] = (_Float16)v;
            }
        }
    }
}

// ---------------------------------------------------------------------------
// Final GEMM fused with layer-4 dot: net[m] += sum_n relu(A@W2^T+b2)[m,n]*w3[n]
// Same dbuf K-loop; epilogue reduces across tile columns and atomicAdds.
// ---------------------------------------------------------------------------
__global__ __launch_bounds__(256)
void gemm_dot(const _Float16* __restrict__ A, const _Float16* __restrict__ Bt,
              const float* __restrict__ bias, const _Float16* __restrict__ w3,
              float* __restrict__ net, int M, int N, int K) {
    __shared__ _Float16 sA[2][128 * 32];
    __shared__ _Float16 sB[2][128 * 32];

    const int tid = threadIdx.x;
    const int lane = tid & 63;
    const int wave = tid >> 6;
    const int wm = wave >> 1;
    const int wn = wave & 1;
    const int quad = lane >> 4;
    const int r16 = lane & 15;

    int mt, nt;
    tile_map(blockIdx.x, M >> 7, N >> 7, mt, nt);
    const int m0 = mt * 128;
    const int n0 = nt * 128;

    const int srow = (lane >> 2);
    const int scol = (lane & 3) * 8;
    const _Float16* gA0 = A + (size_t)(m0 + wave * 32 + srow) * K + scol;
    const _Float16* gA1 = gA0 + (size_t)16 * K;
    const _Float16* gB0 = Bt + (size_t)(n0 + wave * 32 + srow) * K + scol;
    const _Float16* gB1 = gB0 + (size_t)16 * K;
    const int ldsOff0 = (wave * 32) * 32;
    const int ldsOff1 = (wave * 32 + 16) * 32;

    v4f acc[4][4];
#pragma unroll
    for (int i = 0; i < 4; ++i)
#pragma unroll
        for (int j = 0; j < 4; ++j) acc[i][j] = (v4f)0.f;

    const int NT = K >> 5;
    async_copy16(gA0, &sA[0][ldsOff0]);
    async_copy16(gA1, &sA[0][ldsOff1]);
    async_copy16(gB0, &sB[0][ldsOff0]);
    async_copy16(gB1, &sB[0][ldsOff1]);

    for (int kt = 0; kt < NT; ++kt) {
        const int cur = kt & 1;
        __syncthreads();
        if (kt + 1 < NT) {
            const int k0 = (kt + 1) << 5;
            async_copy16(gA0 + k0, &sA[cur ^ 1][ldsOff0]);
            async_copy16(gA1 + k0, &sA[cur ^ 1][ldsOff1]);
            async_copy16(gB0 + k0, &sB[cur ^ 1][ldsOff0]);
            async_copy16(gB1 + k0, &sB[cur ^ 1][ldsOff1]);
        }

        v8h af[4], bf[4];
#pragma unroll
        for (int i = 0; i < 4; ++i)
            af[i] = *(const v8h*)&sA[cur][(wm * 64 + i * 16 + r16) * 32 + quad * 8];
#pragma unroll
        for (int i = 0; i < 4; ++i)
            bf[i] = *(const v8h*)&sB[cur][(wn * 64 + i * 16 + r16) * 32 + quad * 8];
#pragma unroll
        for (int mi = 0; mi < 4; ++mi)
#pragma unroll
            for (int ni = 0; ni < 4; ++ni)
                acc[mi][ni] = __builtin_amdgcn_mfma_f32_16x16x32_f16(
                    af[mi], bf[ni], acc[mi][ni], 0, 0, 0);
    }

    float bv[4], w3v[4];
#pragma unroll
    for (int ni = 0; ni < 4; ++ni) {
        int col = n0 + wn * 64 + ni * 16 + r16;
        bv[ni] = bias[col];
        w3v[ni] = (float)w3[col];
    }

#pragma unroll
    for (int mi = 0; mi < 4; ++mi) {
#pragma unroll
        for (int i = 0; i < 4; ++i) {
            float t = 0.f;
#pragma unroll
            for (int ni = 0; ni < 4; ++ni) {
                float v = fmaxf(acc[mi][ni][i] + bv[ni], 0.f);
                t = fmaf(v, w3v[ni], t);
            }
#pragma unroll
            for (int off = 1; off < 16; off <<= 1) t += __shfl_xor(t, off);
            if (r16 == 0) {
                int row = m0 + wm * 64 + mi * 16 + quad * 4 + i;
                atomicAdd(&net[row], t);
            }
        }
    }
}

// ---------------------------------------------------------------------------
// scan: y_t = a*y_{t-1} + b*c1_t + (net_t + b3) ; out = [y0; ys]
// ---------------------------------------------------------------------------
__global__ void scan_kernel(const float* __restrict__ net,
                            const float* __restrict__ c1,
                            const float* __restrict__ u,
                            const float* __restrict__ pa,
                            const float* __restrict__ pb,
                            const float* __restrict__ pb3,
                            float* __restrict__ out) {
    const int bidx = threadIdx.x;  // 0..255
    const float a = pa[0];
    const float b = pb[0];
    const float b3 = pb3[0];
    float y = u[(size_t)bidx * F_DIM];  // u[0, b, 0]
    out[bidx] = y;
#pragma unroll 8
    for (int t = 0; t < T_DIM; ++t) {
        float z = fmaf(b, c1[t * B_DIM + bidx], net[t * B_DIM + bidx] + b3);
        y = fmaf(a, y, z);
        out[(t + 1) * B_DIM + bidx] = y;
    }
}

// ---------------------------------------------------------------------------
extern "C" void kernel_launch(void* const* d_in, const int* in_sizes, int n_in,
                              void* d_out, int out_size, void* d_ws, size_t ws_size,
                              hipStream_t stream) {
    const float* u = (const float*)d_in[0];
    const float* pa = (const float*)d_in[1];
    const float* pb = (const float*)d_in[2];
    const float* W0 = (const float*)d_in[3];
    const float* b0 = (const float*)d_in[4];
    const float* W1 = (const float*)d_in[5];
    const float* b1 = (const float*)d_in[6];
    const float* W2 = (const float*)d_in[7];
    const float* b2 = (const float*)d_in[8];
    const float* W3 = (const float*)d_in[9];
    const float* b3 = (const float*)d_in[10];
    float* out = (float*)d_out;

    char* ws = (char*)d_ws;
    size_t off = 0;
    auto alloc = [&](size_t bytes) -> void* {
        void* p = ws + off;
        off += (bytes + 255) & ~(size_t)255;
        return p;
    };

    // ---- fixed residents (~5.8 MB) ----
    float* net = (float*)alloc((size_t)M_ROWS * 4);
    float* c1 = (float*)alloc((size_t)M_ROWS * 4);
    _Float16* W0T = (_Float16*)alloc((size_t)IN_DIM * H_DIM * 2);
    _Float16* W1T = (_Float16*)alloc((size_t)H_DIM * H_DIM * 2);
    _Float16* W2T = (_Float16*)alloc((size_t)H_DIM * H_DIM * 2);
    _Float16* W3h = (_Float16*)alloc((size_t)H_DIM * 2);

    // ---- chunk rows: multiple of 1024 so m-tiles per chunk are divisible
    //      by 8 (keeps the XCD swizzle path); X+HA+HB = 4608 B/row ----
    const size_t per_row = 512 + 2048 + 2048;
    size_t avail = (ws_size > off + 65536) ? (ws_size - off - 65536) : 0;
    long Rl = (long)(avail / per_row);
    Rl = (Rl / 1024) * 1024;
    if (Rl < 128) Rl = 128;  // last-resort tiny chunk (fallback tile map)
    if (Rl > M_ROWS) Rl = M_ROWS;
    const int R = (int)Rl;

    _Float16* Xc = (_Float16*)alloc((size_t)R * IN_DIM * 2);
    _Float16* HAc = (_Float16*)alloc((size_t)R * H_DIM * 2);
    _Float16* HBc = (_Float16*)alloc((size_t)R * H_DIM * 2);

    // ---- weights once per call ----
    wt_kernel<<<256, 256, 0, stream>>>(W0, W0T, IN_DIM, H_DIM, IN_DIM * H_DIM);
    wt_kernel<<<512, 256, 0, stream>>>(W1, W1T, H_DIM, H_DIM, H_DIM * H_DIM);
    wt_kernel<<<512, 256, 0, stream>>>(W2, W2T, H_DIM, H_DIM, H_DIM * H_DIM);
    wt_kernel<<<4, 256, 0, stream>>>(W3, W3h, H_DIM, 1, H_DIM);
    zero_kernel<<<M_ROWS / 256, 256, 0, stream>>>(net, M_ROWS);

    // ---- chunked MLP pipeline ----
    for (int r0 = 0; r0 < M_ROWS; r0 += R) {
        int Mc = M_ROWS - r0;
        if (Mc > R) Mc = R;
        int nElem = Mc * F_DIM;
        int pgrid = (nElem + 256 * 8 - 1) / (256 * 8);
        if (pgrid > 2048) pgrid = 2048;
        prep_u_kernel<<<pgrid, 256, 0, stream>>>(u + (size_t)r0 * F_DIM, Xc,
                                                 c1 + r0, nElem);

        dim3 blk(256);
        dim3 grd((Mc / 128) * (H_DIM / 128));  // 1D, swizzled in-kernel
        gemm_f16<<<grd, blk, 0, stream>>>(Xc, W0T, b0, HAc, Mc, H_DIM, IN_DIM);
        gemm_f16<<<grd, blk, 0, stream>>>(HAc, W1T, b1, HBc, Mc, H_DIM, H_DIM);
        gemm_dot<<<grd, blk, 0, stream>>>(HBc, W2T, b2, W3h, net + r0, Mc,
                                          H_DIM, H_DIM);
    }

    // ---- scan ----
    scan_kernel<<<1, 256, 0, stream>>>(net, c1, u, pa, pb, b3, out);
}

// Round 6
// 1171.832 us; speedup vs baseline: 1.1801x; 1.0057x over previous
//
#include <hip/hip_runtime.h>
#include <hip/hip_fp16.h>

typedef _Float16 v8h __attribute__((ext_vector_type(8)));
typedef float v4f __attribute__((ext_vector_type(4)));

#define T_DIM 512
#define B_DIM 256
#define F_DIM 258
#define IN_DIM 256
#define H_DIM 1024
#define M_ROWS (T_DIM * B_DIM) /* 131072 */

// async global->LDS, 16B per lane; lds dest = wave-uniform base + lane*16
__device__ __forceinline__ void async_copy16(const void* g, void* l) {
    __builtin_amdgcn_global_load_lds(
        (const __attribute__((address_space(1))) void*)g,
        (__attribute__((address_space(3))) void*)l, 16, 0, 0);
}

// XCD-aware tile map [R4: FETCH_SIZE 939->185 MB — keep]
__device__ __forceinline__ void tile_map(int b, int nM, int nN, int& mt, int& nt) {
    if (((nM & 7) == 0) && (nN == 8)) {
        int xcd = b & 7;
        int l = b >> 3;
        int mpx = nM >> 3;
        mt = xcd * mpx + (l >> 3);
        nt = l & 7;
    } else {
        mt = b / nN;
        nt = b - mt * nN;
    }
}

// ---------------------------------------------------------------------------
// prep (per chunk): u_chunk (Mc, 258) fp32 -> X_chunk (Mc, 256) fp16 + c1 seg
// ---------------------------------------------------------------------------
__global__ void prep_u_kernel(const float* __restrict__ u,
                              _Float16* __restrict__ X,
                              float* __restrict__ c1, int n) {
    int i = blockIdx.x * blockDim.x + threadIdx.x;
    int stride = gridDim.x * blockDim.x;
    for (; i < n; i += stride) {
        float v = u[i];
        unsigned r = (unsigned)i / 258u;
        unsigned c = (unsigned)i - r * 258u;
        if (c >= 2u) {
            X[r * 256u + (c - 2u)] = (_Float16)v;
        } else if (c == 1u) {
            c1[r] = v;
        }
    }
}

// ---------------------------------------------------------------------------
// weight convert + transpose: W (K x N) fp32 -> Wt (N x K) fp16
// ---------------------------------------------------------------------------
__global__ void wt_kernel(const float* __restrict__ W, _Float16* __restrict__ Wt,
                          int K, int N, int total) {
    int i = blockIdx.x * blockDim.x + threadIdx.x;
    int stride = gridDim.x * blockDim.x;
    for (; i < total; i += stride) {
        int k = i / N;
        int n = i - k * N;
        Wt[(size_t)n * K + k] = (_Float16)W[i];
    }
}

__global__ void zero_kernel(float* __restrict__ p, int n) {
    int i = blockIdx.x * blockDim.x + threadIdx.x;
    if (i < n) p[i] = 0.f;
}

// ---------------------------------------------------------------------------
// GEMM: C[M,N] = relu(A[M,K] @ Bt[N,K]^T + bias[N])
// 128x128 tile, BK=32, 256 threads, lds-dma, XCD swizzle, dbuf prefetch.
// R6: XOR bank swizzle — LDS chunk (row, c) holds k-chunk c ^ ((row>>1)&3).
// Source-side permutation (lds-dma dest must stay linear). Read uses
// qsw = quad ^ ((r16>>1)&3): 16 lanes cover all 8 chunk positions -> 2-way.
// ---------------------------------------------------------------------------
__global__ __launch_bounds__(256)
void gemm_f16(const _Float16* __restrict__ A, const _Float16* __restrict__ Bt,
              const float* __restrict__ bias, _Float16* __restrict__ C,
              int M, int N, int K) {
    __shared__ _Float16 sA[2][128 * 32];
    __shared__ _Float16 sB[2][128 * 32];

    const int tid = threadIdx.x;
    const int lane = tid & 63;
    const int wave = tid >> 6;
    const int wm = wave >> 1;
    const int wn = wave & 1;
    const int quad = lane >> 4;
    const int r16 = lane & 15;

    int mt, nt;
    tile_map(blockIdx.x, M >> 7, N >> 7, mt, nt);
    const int m0 = mt * 128;
    const int n0 = nt * 128;

    const int srow = (lane >> 2);                         // 0..15
    const int scol = (((lane & 3) ^ ((srow >> 1) & 3)) * 8);  // swizzled k-chunk
    const _Float16* gA0 = A + (size_t)(m0 + wave * 32 + srow) * K + scol;
    const _Float16* gA1 = gA0 + (size_t)16 * K;
    const _Float16* gB0 = Bt + (size_t)(n0 + wave * 32 + srow) * K + scol;
    const _Float16* gB1 = gB0 + (size_t)16 * K;
    const int ldsOff0 = (wave * 32) * 32;
    const int ldsOff1 = (wave * 32 + 16) * 32;

    const int qswA = (quad ^ ((r16 >> 1) & 3)) * 8;  // read-side swizzle

    v4f acc[4][4];
#pragma unroll
    for (int i = 0; i < 4; ++i)
#pragma unroll
        for (int j = 0; j < 4; ++j) acc[i][j] = (v4f)0.f;

    const int NT = K >> 5;
    async_copy16(gA0, &sA[0][ldsOff0]);
    async_copy16(gA1, &sA[0][ldsOff1]);
    async_copy16(gB0, &sB[0][ldsOff0]);
    async_copy16(gB1, &sB[0][ldsOff1]);

    for (int kt = 0; kt < NT; ++kt) {
        const int cur = kt & 1;
        __syncthreads();               // publishes tile kt in buf cur
        if (kt + 1 < NT) {
            const int k0 = (kt + 1) << 5;
            async_copy16(gA0 + k0, &sA[cur ^ 1][ldsOff0]);
            async_copy16(gA1 + k0, &sA[cur ^ 1][ldsOff1]);
            async_copy16(gB0 + k0, &sB[cur ^ 1][ldsOff0]);
            async_copy16(gB1 + k0, &sB[cur ^ 1][ldsOff1]);
        }

        v8h af[4], bf[4];
#pragma unroll
        for (int i = 0; i < 4; ++i)
            af[i] = *(const v8h*)&sA[cur][(wm * 64 + i * 16 + r16) * 32 + qswA];
#pragma unroll
        for (int i = 0; i < 4; ++i)
            bf[i] = *(const v8h*)&sB[cur][(wn * 64 + i * 16 + r16) * 32 + qswA];
#pragma unroll
        for (int mi = 0; mi < 4; ++mi)
#pragma unroll
            for (int ni = 0; ni < 4; ++ni)
                acc[mi][ni] = __builtin_amdgcn_mfma_f32_16x16x32_f16(
                    af[mi], bf[ni], acc[mi][ni], 0, 0, 0);
    }

    float bv[4];
#pragma unroll
    for (int ni = 0; ni < 4; ++ni) bv[ni] = bias[n0 + wn * 64 + ni * 16 + r16];

#pragma unroll
    for (int mi = 0; mi < 4; ++mi) {
#pragma unroll
        for (int ni = 0; ni < 4; ++ni) {
#pragma unroll
            for (int i = 0; i < 4; ++i) {
                int row = m0 + wm * 64 + mi * 16 + quad * 4 + i;
                int col = n0 + wn * 64 + ni * 16 + r16;
                float v = fmaxf(acc[mi][ni][i] + bv[ni], 0.f);
                C[(size_t)row * N + col] = (_Float16)v;
            }
        }
    }
}

// ---------------------------------------------------------------------------
// Final GEMM fused with layer-4 dot: net[m] += sum_n relu(A@W2^T+b2)[m,n]*w3[n]
// ---------------------------------------------------------------------------
__global__ __launch_bounds__(256)
void gemm_dot(const _Float16* __restrict__ A, const _Float16* __restrict__ Bt,
              const float* __restrict__ bias, const _Float16* __restrict__ w3,
              float* __restrict__ net, int M, int N, int K) {
    __shared__ _Float16 sA[2][128 * 32];
    __shared__ _Float16 sB[2][128 * 32];

    const int tid = threadIdx.x;
    const int lane = tid & 63;
    const int wave = tid >> 6;
    const int wm = wave >> 1;
    const int wn = wave & 1;
    const int quad = lane >> 4;
    const int r16 = lane & 15;

    int mt, nt;
    tile_map(blockIdx.x, M >> 7, N >> 7, mt, nt);
    const int m0 = mt * 128;
    const int n0 = nt * 128;

    const int srow = (lane >> 2);
    const int scol = (((lane & 3) ^ ((srow >> 1) & 3)) * 8);
    const _Float16* gA0 = A + (size_t)(m0 + wave * 32 + srow) * K + scol;
    const _Float16* gA1 = gA0 + (size_t)16 * K;
    const _Float16* gB0 = Bt + (size_t)(n0 + wave * 32 + srow) * K + scol;
    const _Float16* gB1 = gB0 + (size_t)16 * K;
    const int ldsOff0 = (wave * 32) * 32;
    const int ldsOff1 = (wave * 32 + 16) * 32;

    const int qswA = (quad ^ ((r16 >> 1) & 3)) * 8;

    v4f acc[4][4];
#pragma unroll
    for (int i = 0; i < 4; ++i)
#pragma unroll
        for (int j = 0; j < 4; ++j) acc[i][j] = (v4f)0.f;

    const int NT = K >> 5;
    async_copy16(gA0, &sA[0][ldsOff0]);
    async_copy16(gA1, &sA[0][ldsOff1]);
    async_copy16(gB0, &sB[0][ldsOff0]);
    async_copy16(gB1, &sB[0][ldsOff1]);

    for (int kt = 0; kt < NT; ++kt) {
        const int cur = kt & 1;
        __syncthreads();
        if (kt + 1 < NT) {
            const int k0 = (kt + 1) << 5;
            async_copy16(gA0 + k0, &sA[cur ^ 1][ldsOff0]);
            async_copy16(gA1 + k0, &sA[cur ^ 1][ldsOff1]);
            async_copy16(gB0 + k0, &sB[cur ^ 1][ldsOff0]);
            async_copy16(gB1 + k0, &sB[cur ^ 1][ldsOff1]);
        }

        v8h af[4], bf[4];
#pragma unroll
        for (int i = 0; i < 4; ++i)
            af[i] = *(const v8h*)&sA[cur][(wm * 64 + i * 16 + r16) * 32 + qswA];
#pragma unroll
        for (int i = 0; i < 4; ++i)
            bf[i] = *(const v8h*)&sB[cur][(wn * 64 + i * 16 + r16) * 32 + qswA];
#pragma unroll
        for (int mi = 0; mi < 4; ++mi)
#pragma unroll
            for (int ni = 0; ni < 4; ++ni)
                acc[mi][ni] = __builtin_amdgcn_mfma_f32_16x16x32_f16(
                    af[mi], bf[ni], acc[mi][ni], 0, 0, 0);
    }

    float bv[4], w3v[4];
#pragma unroll
    for (int ni = 0; ni < 4; ++ni) {
        int col = n0 + wn * 64 + ni * 16 + r16;
        bv[ni] = bias[col];
        w3v[ni] = (float)w3[col];
    }

#pragma unroll
    for (int mi = 0; mi < 4; ++mi) {
#pragma unroll
        for (int i = 0; i < 4; ++i) {
            float t = 0.f;
#pragma unroll
            for (int ni = 0; ni < 4; ++ni) {
                float v = fmaxf(acc[mi][ni][i] + bv[ni], 0.f);
                t = fmaf(v, w3v[ni], t);
            }
#pragma unroll
            for (int off = 1; off < 16; off <<= 1) t += __shfl_xor(t, off);
            if (r16 == 0) {
                int row = m0 + wm * 64 + mi * 16 + quad * 4 + i;
                atomicAdd(&net[row], t);
            }
        }
    }
}

// ---------------------------------------------------------------------------
// scan: y_t = a*y_{t-1} + b*c1_t + (net_t + b3) ; out = [y0; ys]
// ---------------------------------------------------------------------------
__global__ void scan_kernel(const float* __restrict__ net,
                            const float* __restrict__ c1,
                            const float* __restrict__ u,
                            const float* __restrict__ pa,
                            const float* __restrict__ pb,
                            const float* __restrict__ pb3,
                            float* __restrict__ out) {
    const int bidx = threadIdx.x;  // 0..255
    const float a = pa[0];
    const float b = pb[0];
    const float b3 = pb3[0];
    float y = u[(size_t)bidx * F_DIM];  // u[0, b, 0]
    out[bidx] = y;
#pragma unroll 8
    for (int t = 0; t < T_DIM; ++t) {
        float z = fmaf(b, c1[t * B_DIM + bidx], net[t * B_DIM + bidx] + b3);
        y = fmaf(a, y, z);
        out[(t + 1) * B_DIM + bidx] = y;
    }
}

// ---------------------------------------------------------------------------
extern "C" void kernel_launch(void* const* d_in, const int* in_sizes, int n_in,
                              void* d_out, int out_size, void* d_ws, size_t ws_size,
                              hipStream_t stream) {
    const float* u = (const float*)d_in[0];
    const float* pa = (const float*)d_in[1];
    const float* pb = (const float*)d_in[2];
    const float* W0 = (const float*)d_in[3];
    const float* b0 = (const float*)d_in[4];
    const float* W1 = (const float*)d_in[5];
    const float* b1 = (const float*)d_in[6];
    const float* W2 = (const float*)d_in[7];
    const float* b2 = (const float*)d_in[8];
    const float* W3 = (const float*)d_in[9];
    const float* b3 = (const float*)d_in[10];
    float* out = (float*)d_out;

    char* ws = (char*)d_ws;
    size_t off = 0;
    auto alloc = [&](size_t bytes) -> void* {
        void* p = ws + off;
        off += (bytes + 255) & ~(size_t)255;
        return p;
    };

    // ---- fixed residents (~5.8 MB) ----
    float* net = (float*)alloc((size_t)M_ROWS * 4);
    float* c1 = (float*)alloc((size_t)M_ROWS * 4);
    _Float16* W0T = (_Float16*)alloc((size_t)IN_DIM * H_DIM * 2);
    _Float16* W1T = (_Float16*)alloc((size_t)H_DIM * H_DIM * 2);
    _Float16* W2T = (_Float16*)alloc((size_t)H_DIM * H_DIM * 2);
    _Float16* W3h = (_Float16*)alloc((size_t)H_DIM * 2);

    // ---- chunk rows: multiple of 1024 (XCD swizzle path) ----
    const size_t per_row = 512 + 2048 + 2048;
    size_t avail = (ws_size > off + 65536) ? (ws_size - off - 65536) : 0;
    long Rl = (long)(avail / per_row);
    Rl = (Rl / 1024) * 1024;
    if (Rl < 128) Rl = 128;
    if (Rl > M_ROWS) Rl = M_ROWS;
    const int R = (int)Rl;

    _Float16* Xc = (_Float16*)alloc((size_t)R * IN_DIM * 2);
    _Float16* HAc = (_Float16*)alloc((size_t)R * H_DIM * 2);
    _Float16* HBc = (_Float16*)alloc((size_t)R * H_DIM * 2);

    // ---- weights once per call ----
    wt_kernel<<<256, 256, 0, stream>>>(W0, W0T, IN_DIM, H_DIM, IN_DIM * H_DIM);
    wt_kernel<<<512, 256, 0, stream>>>(W1, W1T, H_DIM, H_DIM, H_DIM * H_DIM);
    wt_kernel<<<512, 256, 0, stream>>>(W2, W2T, H_DIM, H_DIM, H_DIM * H_DIM);
    wt_kernel<<<4, 256, 0, stream>>>(W3, W3h, H_DIM, 1, H_DIM);
    zero_kernel<<<M_ROWS / 256, 256, 0, stream>>>(net, M_ROWS);

    // ---- chunked MLP pipeline ----
    for (int r0 = 0; r0 < M_ROWS; r0 += R) {
        int Mc = M_ROWS - r0;
        if (Mc > R) Mc = R;
        int nElem = Mc * F_DIM;
        int pgrid = (nElem + 256 * 8 - 1) / (256 * 8);
        if (pgrid > 2048) pgrid = 2048;
        prep_u_kernel<<<pgrid, 256, 0, stream>>>(u + (size_t)r0 * F_DIM, Xc,
                                                 c1 + r0, nElem);

        dim3 blk(256);
        dim3 grd((Mc / 128) * (H_DIM / 128));  // 1D, swizzled in-kernel
        gemm_f16<<<grd, blk, 0, stream>>>(Xc, W0T, b0, HAc, Mc, H_DIM, IN_DIM);
        gemm_f16<<<grd, blk, 0, stream>>>(HAc, W1T, b1, HBc, Mc, H_DIM, H_DIM);
        gemm_dot<<<grd, blk, 0, stream>>>(HBc, W2T, b2, W3h, net + r0, Mc,
                                          H_DIM, H_DIM);
    }

    // ---- scan ----
    scan_kernel<<<1, 256, 0, stream>>>(net, c1, u, pa, pb, b3, out);
}

// Round 7
// 1147.734 us; speedup vs baseline: 1.2048x; 1.0210x over previous
//
#include <hip/hip_runtime.h>
#include <hip/hip_fp16.h>

typedef _Float16 v8h __attribute__((ext_vector_type(8)));
typedef float v4f __attribute__((ext_vector_type(4)));

#define T_DIM 512
#define B_DIM 256
#define F_DIM 258
#define IN_DIM 256
#define H_DIM 1024
#define M_ROWS (T_DIM * B_DIM) /* 131072 */

// async global->LDS, 16B per lane; lds dest = wave-uniform base + lane*16
__device__ __forceinline__ void async_copy16(const void* g, void* l) {
    __builtin_amdgcn_global_load_lds(
        (const __attribute__((address_space(1))) void*)g,
        (__attribute__((address_space(3))) void*)l, 16, 0, 0);
}

// XCD-aware tile map [R4: FETCH_SIZE 939->185 MB — keep]
__device__ __forceinline__ void tile_map(int b, int nM, int nN, int& mt, int& nt) {
    if (((nM & 7) == 0) && (nN == 8)) {
        int xcd = b & 7;
        int l = b >> 3;
        int mpx = nM >> 3;
        mt = xcd * mpx + (l >> 3);
        nt = l & 7;
    } else {
        mt = b / nN;
        nt = b - mt * nN;
    }
}

// ---------------------------------------------------------------------------
// prep: u (Mc, 258) fp32 -> X (Mc, 256) fp16 + c1 seg
// ---------------------------------------------------------------------------
__global__ void prep_u_kernel(const float* __restrict__ u,
                              _Float16* __restrict__ X,
                              float* __restrict__ c1, int n) {
    int i = blockIdx.x * blockDim.x + threadIdx.x;
    int stride = gridDim.x * blockDim.x;
    for (; i < n; i += stride) {
        float v = u[i];
        unsigned r = (unsigned)i / 258u;
        unsigned c = (unsigned)i - r * 258u;
        if (c >= 2u) {
            X[r * 256u + (c - 2u)] = (_Float16)v;
        } else if (c == 1u) {
            c1[r] = v;
        }
    }
}

// ---------------------------------------------------------------------------
// weight -> fragment-major fp16. W (K x N fp32). Frag f=(g*KC+kc)*4+i holds
// cols g*64+i*16+(l&15), k = kc*32+(l>>4)*8+j  (exact MFMA B-operand order).
// BF[f*512 + l*8 + j]
// ---------------------------------------------------------------------------
__global__ void wt_frag_kernel(const float* __restrict__ W,
                               _Float16* __restrict__ BF, int K, int N) {
    int idx = blockIdx.x * blockDim.x + threadIdx.x;  // one per (frag, lane)
    int total = (N >> 6) * (K >> 5) * 4 * 64;
    if (idx >= total) return;
    int l = idx & 63;
    int f = idx >> 6;
    int i = f & 3;
    int gk = f >> 2;
    int KC = K >> 5;
    int g = gk / KC, kc = gk - g * KC;
    int col = g * 64 + i * 16 + (l & 15);
    int krow = kc * 32 + (l >> 4) * 8;
    _Float16 tmp[8];
#pragma unroll
    for (int j = 0; j < 8; ++j) tmp[j] = (_Float16)W[(size_t)(krow + j) * N + col];
    *(v8h*)&BF[(size_t)idx * 8] = *(v8h*)tmp;
}

// W (K x 1) -> fp16 vector
__global__ void wt_vec_kernel(const float* __restrict__ W,
                              _Float16* __restrict__ Wh, int K) {
    int i = blockIdx.x * blockDim.x + threadIdx.x;
    if (i < K) Wh[i] = (_Float16)W[i];
}

__global__ void zero_kernel(float* __restrict__ p, int n) {
    int i = blockIdx.x * blockDim.x + threadIdx.x;
    if (i < n) p[i] = 0.f;
}

// ---------------------------------------------------------------------------
// GEMM: C[M,N] = relu(A[M,K] @ W^T + bias), W as fragment-major BF.
// A: LDS (dma, dbuf, XOR swizzle). B: registers direct from L2 (prefetch +1).
// ---------------------------------------------------------------------------
__global__ __launch_bounds__(256)
void gemm_f16(const _Float16* __restrict__ A, const _Float16* __restrict__ BF,
              const float* __restrict__ bias, _Float16* __restrict__ C,
              int M, int N, int K) {
    __shared__ _Float16 sA[2][128 * 32];

    const int tid = threadIdx.x;
    const int lane = tid & 63;
    const int wave = tid >> 6;
    const int wm = wave >> 1;
    const int wn = wave & 1;
    const int quad = lane >> 4;
    const int r16 = lane & 15;

    int mt, nt;
    tile_map(blockIdx.x, M >> 7, N >> 7, mt, nt);
    const int m0 = mt * 128;
    const int n0 = nt * 128;

    // A staging: wave stages rows [wave*32, wave*32+32), source-side swizzle
    const int srow = (lane >> 2);
    const int scol = (((lane & 3) ^ ((srow >> 1) & 3)) * 8);
    const _Float16* gA0 = A + (size_t)(m0 + wave * 32 + srow) * K + scol;
    const _Float16* gA1 = gA0 + (size_t)16 * K;
    const int ldsOff0 = (wave * 32) * 32;
    const int ldsOff1 = (wave * 32 + 16) * 32;
    const int qswA = (quad ^ ((r16 >> 1) & 3)) * 8;  // read-side swizzle

    // B fragment pointer for this wave's 64-col group
    const int KC = K >> 5;
    const int g = nt * 2 + wn;
    const _Float16* BFg = BF + (size_t)g * KC * 4 * 512 + lane * 8;

    v4f acc[4][4];
#pragma unroll
    for (int i = 0; i < 4; ++i)
#pragma unroll
        for (int j = 0; j < 4; ++j) acc[i][j] = (v4f)0.f;

    const int NT = KC;
    async_copy16(gA0, &sA[0][ldsOff0]);
    async_copy16(gA1, &sA[0][ldsOff1]);

    v8h bf_cur[4], bf_next[4];
#pragma unroll
    for (int i = 0; i < 4; ++i) bf_cur[i] = *(const v8h*)&BFg[(size_t)i * 512];

    for (int kt = 0; kt < NT; ++kt) {
        const int cur = kt & 1;
        __syncthreads();               // publishes A tile kt
        const int ktn = (kt + 1 < NT) ? kt + 1 : kt;
#pragma unroll
        for (int i = 0; i < 4; ++i)
            bf_next[i] = *(const v8h*)&BFg[(size_t)(ktn * 4 + i) * 512];
        if (kt + 1 < NT) {
            const int k0 = (kt + 1) << 5;
            async_copy16(gA0 + k0, &sA[cur ^ 1][ldsOff0]);
            async_copy16(gA1 + k0, &sA[cur ^ 1][ldsOff1]);
        }

        v8h af[4];
#pragma unroll
        for (int i = 0; i < 4; ++i)
            af[i] = *(const v8h*)&sA[cur][(wm * 64 + i * 16 + r16) * 32 + qswA];
#pragma unroll
        for (int mi = 0; mi < 4; ++mi)
#pragma unroll
            for (int ni = 0; ni < 4; ++ni)
                acc[mi][ni] = __builtin_amdgcn_mfma_f32_16x16x32_f16(
                    af[mi], bf_cur[ni], acc[mi][ni], 0, 0, 0);
#pragma unroll
        for (int i = 0; i < 4; ++i) bf_cur[i] = bf_next[i];
    }

    float bv[4];
#pragma unroll
    for (int ni = 0; ni < 4; ++ni) bv[ni] = bias[n0 + wn * 64 + ni * 16 + r16];

#pragma unroll
    for (int mi = 0; mi < 4; ++mi) {
#pragma unroll
        for (int ni = 0; ni < 4; ++ni) {
#pragma unroll
            for (int i = 0; i < 4; ++i) {
                int row = m0 + wm * 64 + mi * 16 + quad * 4 + i;
                int col = n0 + wn * 64 + ni * 16 + r16;
                float v = fmaxf(acc[mi][ni][i] + bv[ni], 0.f);
                C[(size_t)row * N + col] = (_Float16)v;
            }
        }
    }
}

// ---------------------------------------------------------------------------
// Final GEMM fused with layer-4 dot: net[m] += sum_n relu(A@W2^T+b2)[m,n]*w3[n]
// ---------------------------------------------------------------------------
__global__ __launch_bounds__(256)
void gemm_dot(const _Float16* __restrict__ A, const _Float16* __restrict__ BF,
              const float* __restrict__ bias, const _Float16* __restrict__ w3,
              float* __restrict__ net, int M, int N, int K) {
    __shared__ _Float16 sA[2][128 * 32];

    const int tid = threadIdx.x;
    const int lane = tid & 63;
    const int wave = tid >> 6;
    const int wm = wave >> 1;
    const int wn = wave & 1;
    const int quad = lane >> 4;
    const int r16 = lane & 15;

    int mt, nt;
    tile_map(blockIdx.x, M >> 7, N >> 7, mt, nt);
    const int m0 = mt * 128;
    const int n0 = nt * 128;

    const int srow = (lane >> 2);
    const int scol = (((lane & 3) ^ ((srow >> 1) & 3)) * 8);
    const _Float16* gA0 = A + (size_t)(m0 + wave * 32 + srow) * K + scol;
    const _Float16* gA1 = gA0 + (size_t)16 * K;
    const int ldsOff0 = (wave * 32) * 32;
    const int ldsOff1 = (wave * 32 + 16) * 32;
    const int qswA = (quad ^ ((r16 >> 1) & 3)) * 8;

    const int KC = K >> 5;
    const int g = nt * 2 + wn;
    const _Float16* BFg = BF + (size_t)g * KC * 4 * 512 + lane * 8;

    v4f acc[4][4];
#pragma unroll
    for (int i = 0; i < 4; ++i)
#pragma unroll
        for (int j = 0; j < 4; ++j) acc[i][j] = (v4f)0.f;

    const int NT = KC;
    async_copy16(gA0, &sA[0][ldsOff0]);
    async_copy16(gA1, &sA[0][ldsOff1]);

    v8h bf_cur[4], bf_next[4];
#pragma unroll
    for (int i = 0; i < 4; ++i) bf_cur[i] = *(const v8h*)&BFg[(size_t)i * 512];

    for (int kt = 0; kt < NT; ++kt) {
        const int cur = kt & 1;
        __syncthreads();
        const int ktn = (kt + 1 < NT) ? kt + 1 : kt;
#pragma unroll
        for (int i = 0; i < 4; ++i)
            bf_next[i] = *(const v8h*)&BFg[(size_t)(ktn * 4 + i) * 512];
        if (kt + 1 < NT) {
            const int k0 = (kt + 1) << 5;
            async_copy16(gA0 + k0, &sA[cur ^ 1][ldsOff0]);
            async_copy16(gA1 + k0, &sA[cur ^ 1][ldsOff1]);
        }

        v8h af[4];
#pragma unroll
        for (int i = 0; i < 4; ++i)
            af[i] = *(const v8h*)&sA[cur][(wm * 64 + i * 16 + r16) * 32 + qswA];
#pragma unroll
        for (int mi = 0; mi < 4; ++mi)
#pragma unroll
            for (int ni = 0; ni < 4; ++ni)
                acc[mi][ni] = __builtin_amdgcn_mfma_f32_16x16x32_f16(
                    af[mi], bf_cur[ni], acc[mi][ni], 0, 0, 0);
#pragma unroll
        for (int i = 0; i < 4; ++i) bf_cur[i] = bf_next[i];
    }

    float bv[4], w3v[4];
#pragma unroll
    for (int ni = 0; ni < 4; ++ni) {
        int col = n0 + wn * 64 + ni * 16 + r16;
        bv[ni] = bias[col];
        w3v[ni] = (float)w3[col];
    }

#pragma unroll
    for (int mi = 0; mi < 4; ++mi) {
#pragma unroll
        for (int i = 0; i < 4; ++i) {
            float t = 0.f;
#pragma unroll
            for (int ni = 0; ni < 4; ++ni) {
                float v = fmaxf(acc[mi][ni][i] + bv[ni], 0.f);
                t = fmaf(v, w3v[ni], t);
            }
#pragma unroll
            for (int off = 1; off < 16; off <<= 1) t += __shfl_xor(t, off);
            if (r16 == 0) {
                int row = m0 + wm * 64 + mi * 16 + quad * 4 + i;
                atomicAdd(&net[row], t);
            }
        }
    }
}

// ---------------------------------------------------------------------------
// scan: y_t = a*y_{t-1} + b*c1_t + (net_t + b3) ; out = [y0; ys]
// ---------------------------------------------------------------------------
__global__ void scan_kernel(const float* __restrict__ net,
                            const float* __restrict__ c1,
                            const float* __restrict__ u,
                            const float* __restrict__ pa,
                            const float* __restrict__ pb,
                            const float* __restrict__ pb3,
                            float* __restrict__ out) {
    const int bidx = threadIdx.x;  // 0..255
    const float a = pa[0];
    const float b = pb[0];
    const float b3 = pb3[0];
    float y = u[(size_t)bidx * F_DIM];  // u[0, b, 0]
    out[bidx] = y;
#pragma unroll 8
    for (int t = 0; t < T_DIM; ++t) {
        float z = fmaf(b, c1[t * B_DIM + bidx], net[t * B_DIM + bidx] + b3);
        y = fmaf(a, y, z);
        out[(t + 1) * B_DIM + bidx] = y;
    }
}

// ---------------------------------------------------------------------------
extern "C" void kernel_launch(void* const* d_in, const int* in_sizes, int n_in,
                              void* d_out, int out_size, void* d_ws, size_t ws_size,
                              hipStream_t stream) {
    const float* u = (const float*)d_in[0];
    const float* pa = (const float*)d_in[1];
    const float* pb = (const float*)d_in[2];
    const float* W0 = (const float*)d_in[3];
    const float* b0 = (const float*)d_in[4];
    const float* W1 = (const float*)d_in[5];
    const float* b1 = (const float*)d_in[6];
    const float* W2 = (const float*)d_in[7];
    const float* b2 = (const float*)d_in[8];
    const float* W3 = (const float*)d_in[9];
    const float* b3 = (const float*)d_in[10];
    float* out = (float*)d_out;

    char* ws = (char*)d_ws;
    size_t off = 0;
    auto alloc = [&](size_t bytes) -> void* {
        void* p = ws + off;
        off += (bytes + 255) & ~(size_t)255;
        return p;
    };

    // ---- fixed residents (~5.8 MB) ----
    float* net = (float*)alloc((size_t)M_ROWS * 4);
    float* c1 = (float*)alloc((size_t)M_ROWS * 4);
    _Float16* W0F = (_Float16*)alloc((size_t)IN_DIM * H_DIM * 2);
    _Float16* W1F = (_Float16*)alloc((size_t)H_DIM * H_DIM * 2);
    _Float16* W2F = (_Float16*)alloc((size_t)H_DIM * H_DIM * 2);
    _Float16* W3h = (_Float16*)alloc((size_t)H_DIM * 2);

    // ---- chunk rows: multiple of 1024 (XCD swizzle path) ----
    const size_t per_row = 512 + 2048 + 2048;
    size_t avail = (ws_size > off + 65536) ? (ws_size - off - 65536) : 0;
    long Rl = (long)(avail / per_row);
    Rl = (Rl / 1024) * 1024;
    if (Rl < 128) Rl = 128;
    if (Rl > M_ROWS) Rl = M_ROWS;
    const int R = (int)Rl;

    _Float16* Xc = (_Float16*)alloc((size_t)R * IN_DIM * 2);
    _Float16* HAc = (_Float16*)alloc((size_t)R * H_DIM * 2);
    _Float16* HBc = (_Float16*)alloc((size_t)R * H_DIM * 2);

    // ---- weights once per call (fragment-major) ----
    wt_frag_kernel<<<(IN_DIM / 32) * (H_DIM / 64), 256, 0, stream>>>(W0, W0F,
                                                                     IN_DIM, H_DIM);
    wt_frag_kernel<<<(H_DIM / 32) * (H_DIM / 64), 256, 0, stream>>>(W1, W1F,
                                                                    H_DIM, H_DIM);
    wt_frag_kernel<<<(H_DIM / 32) * (H_DIM / 64), 256, 0, stream>>>(W2, W2F,
                                                                    H_DIM, H_DIM);
    wt_vec_kernel<<<4, 256, 0, stream>>>(W3, W3h, H_DIM);
    zero_kernel<<<M_ROWS / 256, 256, 0, stream>>>(net, M_ROWS);

    // ---- chunked MLP pipeline ----
    for (int r0 = 0; r0 < M_ROWS; r0 += R) {
        int Mc = M_ROWS - r0;
        if (Mc > R) Mc = R;
        int nElem = Mc * F_DIM;
        int pgrid = (nElem + 256 * 8 - 1) / (256 * 8);
        if (pgrid > 2048) pgrid = 2048;
        prep_u_kernel<<<pgrid, 256, 0, stream>>>(u + (size_t)r0 * F_DIM, Xc,
                                                 c1 + r0, nElem);

        dim3 blk(256);
        dim3 grd((Mc / 128) * (H_DIM / 128));  // 1D, swizzled in-kernel
        gemm_f16<<<grd, blk, 0, stream>>>(Xc, W0F, b0, HAc, Mc, H_DIM, IN_DIM);
        gemm_f16<<<grd, blk, 0, stream>>>(HAc, W1F, b1, HBc, Mc, H_DIM, H_DIM);
        gemm_dot<<<grd, blk, 0, stream>>>(HBc, W2F, b2, W3h, net + r0, Mc,
                                          H_DIM, H_DIM);
    }

    // ---- scan ----
    scan_kernel<<<1, 256, 0, stream>>>(net, c1, u, pa, pb, b3, out);
}

// Round 8
// 1125.182 us; speedup vs baseline: 1.2290x; 1.0200x over previous
//
#include <hip/hip_runtime.h>
#include <hip/hip_fp16.h>

typedef _Float16 v8h __attribute__((ext_vector_type(8)));
typedef _Float16 v4h __attribute__((ext_vector_type(4)));
typedef float v4f __attribute__((ext_vector_type(4)));

#define T_DIM 512
#define B_DIM 256
#define F_DIM 258
#define IN_DIM 256
#define H_DIM 1024
#define M_ROWS (T_DIM * B_DIM) /* 131072 */

// XCD-aware tile map [R4: FETCH_SIZE 939->185 MB — keep]
__device__ __forceinline__ void tile_map(int b, int nM, int nN, int& mt, int& nt) {
    if (((nM & 7) == 0) && (nN == 8)) {
        int xcd = b & 7;
        int l = b >> 3;
        int mpx = nM >> 3;
        mt = xcd * mpx + (l >> 3);
        nt = l & 7;
    } else {
        mt = b / nN;
        nt = b - mt * nN;
    }
}

// ---------------------------------------------------------------------------
// Activations live in blocked "bk8" layout: X[m][k] at
//   ((m>>4)*(K>>3) + (k>>3))*128 + (m&15)*8 + (k&7)
// so a B-operand fragment (lane l: m=l&15, k=(l>>4)*8+j) is one coalesced
// 16B load at blk*128 + (l>>4)*128 + (l&15)*8.
// ---------------------------------------------------------------------------

// prep: u (Mc,258) fp32 -> X bk8 fp16 + c1 seg
__global__ void prep_u_kernel(const float* __restrict__ u,
                              _Float16* __restrict__ X,
                              float* __restrict__ c1, int n) {
    int i = blockIdx.x * blockDim.x + threadIdx.x;
    int stride = gridDim.x * blockDim.x;
    for (; i < n; i += stride) {
        float v = u[i];
        unsigned r = (unsigned)i / 258u;
        unsigned c = (unsigned)i - r * 258u;
        if (c >= 2u) {
            unsigned k = c - 2u;
            X[((r >> 4) * 32u + (k >> 3)) * 128u + (r & 15u) * 8u + (k & 7u)] =
                (_Float16)v;
        } else if (c == 1u) {
            c1[r] = v;
        }
    }
}

// ---------------------------------------------------------------------------
// weight -> fragment-major fp16 (A/B-frag dual layout). W (K x N fp32).
// Frag f=(g*KC+kc)*4+i holds n = g*64+i*16+(l&15), k = kc*32+(l>>4)*8+j.
// ---------------------------------------------------------------------------
__global__ void wt_frag_kernel(const float* __restrict__ W,
                               _Float16* __restrict__ BF, int K, int N) {
    int idx = blockIdx.x * blockDim.x + threadIdx.x;
    int total = (N >> 6) * (K >> 5) * 4 * 64;
    if (idx >= total) return;
    int l = idx & 63;
    int f = idx >> 6;
    int i = f & 3;
    int gk = f >> 2;
    int KC = K >> 5;
    int g = gk / KC, kc = gk - g * KC;
    int col = g * 64 + i * 16 + (l & 15);
    int krow = kc * 32 + (l >> 4) * 8;
    _Float16 tmp[8];
#pragma unroll
    for (int j = 0; j < 8; ++j) tmp[j] = (_Float16)W[(size_t)(krow + j) * N + col];
    *(v8h*)&BF[(size_t)idx * 8] = *(v8h*)tmp;
}

__global__ void wt_vec_kernel(const float* __restrict__ W,
                              _Float16* __restrict__ Wh, int K) {
    int i = blockIdx.x * blockDim.x + threadIdx.x;
    if (i < K) Wh[i] = (_Float16)W[i];
}

__global__ void zero_kernel(float* __restrict__ p, int n) {
    int i = blockIdx.x * blockDim.x + threadIdx.x;
    if (i < n) p[i] = 0.f;
}

// ---------------------------------------------------------------------------
// R8 GEMM: Y^T = W^T @ X^T. NO LDS, NO BARRIERS. Weights = A-operand
// (frag-major, register-direct), activations = B-operand (bk8, register-
// direct). Output written back in bk8 (coalesced 8B/lane packed stores).
// Wave tile: 64(n) x 64(m); block 2x2 waves = 128x128.
// ---------------------------------------------------------------------------
__global__ __launch_bounds__(256, 3)
void gemm_f16(const _Float16* __restrict__ Xb, const _Float16* __restrict__ WF,
              const float* __restrict__ bias, _Float16* __restrict__ Cb,
              int M, int N, int K) {
    const int tid = threadIdx.x;
    const int lane = tid & 63;
    const int wave = tid >> 6;
    const int wm = wave >> 1;
    const int wn = wave & 1;
    const int quad = lane >> 4;
    const int r16 = lane & 15;

    int mt, nt;
    tile_map(blockIdx.x, M >> 7, N >> 7, mt, nt);
    const int m0 = mt * 128;
    const int n0 = nt * 128;

    const int KC8 = K >> 3;   // k-blocks of 8
    const int NT = K >> 5;    // K-iters of 32

    // activation (B-frag) pointers, one per mi
    const int lo_b = (lane >> 4) * 128 + r16 * 8;
    const _Float16* actp[4];
#pragma unroll
    for (int mi = 0; mi < 4; ++mi)
        actp[mi] = Xb + (size_t)((m0 + wm * 64 + mi * 16) >> 4) * KC8 * 128 + lo_b;

    // weight (A-frag) pointer for this wave's 64-col group
    const _Float16* wp = WF + (size_t)(nt * 2 + wn) * NT * 2048 + lane * 8;

    v4f acc[4][4];  // acc[ni][mi]
#pragma unroll
    for (int i = 0; i < 4; ++i)
#pragma unroll
        for (int j = 0; j < 4; ++j) acc[i][j] = (v4f)0.f;

    for (int kt = 0; kt < NT; ++kt) {
        v8h bfrag[4], afrag[4];
#pragma unroll
        for (int mi = 0; mi < 4; ++mi)
            bfrag[mi] = *(const v8h*)(actp[mi] + (size_t)kt * 512);
#pragma unroll
        for (int ni = 0; ni < 4; ++ni)
            afrag[ni] = *(const v8h*)(wp + (size_t)kt * 2048 + ni * 512);
#pragma unroll
        for (int ni = 0; ni < 4; ++ni)
#pragma unroll
            for (int mi = 0; mi < 4; ++mi)
                acc[ni][mi] = __builtin_amdgcn_mfma_f32_16x16x32_f16(
                    afrag[ni], bfrag[mi], acc[ni][mi], 0, 0, 0);
    }

    // epilogue: lane holds n = nb+ni*16+quad*4+i, m = mb+mi*16+r16.
    const int nb = n0 + wn * 64;
    v4f bv[4];
#pragma unroll
    for (int ni = 0; ni < 4; ++ni)
        bv[ni] = *(const v4f*)&bias[nb + ni * 16 + quad * 4];

    const int NC8 = N >> 3;
#pragma unroll
    for (int ni = 0; ni < 4; ++ni) {
        const int nblk = ((nb + ni * 16) >> 3) + (quad >> 1);
#pragma unroll
        for (int mi = 0; mi < 4; ++mi) {
            v4h hv;
#pragma unroll
            for (int i = 0; i < 4; ++i)
                hv[i] = (_Float16)fmaxf(acc[ni][mi][i] + bv[ni][i], 0.f);
            const size_t mblk = (size_t)((m0 + wm * 64 + mi * 16) >> 4);
            _Float16* dst = Cb + (mblk * NC8 + nblk) * 128 + r16 * 8 + (quad & 1) * 4;
            *(v4h*)dst = hv;
        }
    }
}

// ---------------------------------------------------------------------------
// Final GEMM fused with layer-4 dot: net[m] += sum_n relu(...)[m,n]*w3[n]
// Same barrier-free K-loop; reduce across quads (same r16) via shfl_xor.
// ---------------------------------------------------------------------------
__global__ __launch_bounds__(256, 3)
void gemm_dot(const _Float16* __restrict__ Xb, const _Float16* __restrict__ WF,
              const float* __restrict__ bias, const _Float16* __restrict__ w3,
              float* __restrict__ net, int M, int N, int K) {
    const int tid = threadIdx.x;
    const int lane = tid & 63;
    const int wave = tid >> 6;
    const int wm = wave >> 1;
    const int wn = wave & 1;
    const int quad = lane >> 4;
    const int r16 = lane & 15;

    int mt, nt;
    tile_map(blockIdx.x, M >> 7, N >> 7, mt, nt);
    const int m0 = mt * 128;
    const int n0 = nt * 128;

    const int KC8 = K >> 3;
    const int NT = K >> 5;

    const int lo_b = (lane >> 4) * 128 + r16 * 8;
    const _Float16* actp[4];
#pragma unroll
    for (int mi = 0; mi < 4; ++mi)
        actp[mi] = Xb + (size_t)((m0 + wm * 64 + mi * 16) >> 4) * KC8 * 128 + lo_b;

    const _Float16* wp = WF + (size_t)(nt * 2 + wn) * NT * 2048 + lane * 8;

    v4f acc[4][4];
#pragma unroll
    for (int i = 0; i < 4; ++i)
#pragma unroll
        for (int j = 0; j < 4; ++j) acc[i][j] = (v4f)0.f;

    for (int kt = 0; kt < NT; ++kt) {
        v8h bfrag[4], afrag[4];
#pragma unroll
        for (int mi = 0; mi < 4; ++mi)
            bfrag[mi] = *(const v8h*)(actp[mi] + (size_t)kt * 512);
#pragma unroll
        for (int ni = 0; ni < 4; ++ni)
            afrag[ni] = *(const v8h*)(wp + (size_t)kt * 2048 + ni * 512);
#pragma unroll
        for (int ni = 0; ni < 4; ++ni)
#pragma unroll
            for (int mi = 0; mi < 4; ++mi)
                acc[ni][mi] = __builtin_amdgcn_mfma_f32_16x16x32_f16(
                    afrag[ni], bfrag[mi], acc[ni][mi], 0, 0, 0);
    }

    const int nb = n0 + wn * 64;
    v4f bv[4];
    v4h wv[4];
#pragma unroll
    for (int ni = 0; ni < 4; ++ni) {
        bv[ni] = *(const v4f*)&bias[nb + ni * 16 + quad * 4];
        wv[ni] = *(const v4h*)&w3[nb + ni * 16 + quad * 4];
    }

#pragma unroll
    for (int mi = 0; mi < 4; ++mi) {
        float t = 0.f;
#pragma unroll
        for (int ni = 0; ni < 4; ++ni)
#pragma unroll
            for (int i = 0; i < 4; ++i) {
                float v = fmaxf(acc[ni][mi][i] + bv[ni][i], 0.f);
                t = fmaf(v, (float)wv[ni][i], t);
            }
        // sum across quads (lanes sharing r16): full 64-n slice for this wave
        t += __shfl_xor(t, 16);
        t += __shfl_xor(t, 32);
        if (quad == 0) {
            int row = m0 + wm * 64 + mi * 16 + r16;
            atomicAdd(&net[row], t);
        }
    }
}

// ---------------------------------------------------------------------------
// scan: y_t = a*y_{t-1} + b*c1_t + (net_t + b3) ; out = [y0; ys]
// ---------------------------------------------------------------------------
__global__ void scan_kernel(const float* __restrict__ net,
                            const float* __restrict__ c1,
                            const float* __restrict__ u,
                            const float* __restrict__ pa,
                            const float* __restrict__ pb,
                            const float* __restrict__ pb3,
                            float* __restrict__ out) {
    const int bidx = threadIdx.x;  // 0..255
    const float a = pa[0];
    const float b = pb[0];
    const float b3 = pb3[0];
    float y = u[(size_t)bidx * F_DIM];  // u[0, b, 0]
    out[bidx] = y;
#pragma unroll 8
    for (int t = 0; t < T_DIM; ++t) {
        float z = fmaf(b, c1[t * B_DIM + bidx], net[t * B_DIM + bidx] + b3);
        y = fmaf(a, y, z);
        out[(t + 1) * B_DIM + bidx] = y;
    }
}

// ---------------------------------------------------------------------------
extern "C" void kernel_launch(void* const* d_in, const int* in_sizes, int n_in,
                              void* d_out, int out_size, void* d_ws, size_t ws_size,
                              hipStream_t stream) {
    const float* u = (const float*)d_in[0];
    const float* pa = (const float*)d_in[1];
    const float* pb = (const float*)d_in[2];
    const float* W0 = (const float*)d_in[3];
    const float* b0 = (const float*)d_in[4];
    const float* W1 = (const float*)d_in[5];
    const float* b1 = (const float*)d_in[6];
    const float* W2 = (const float*)d_in[7];
    const float* b2 = (const float*)d_in[8];
    const float* W3 = (const float*)d_in[9];
    const float* b3 = (const float*)d_in[10];
    float* out = (float*)d_out;

    char* ws = (char*)d_ws;
    size_t off = 0;
    auto alloc = [&](size_t bytes) -> void* {
        void* p = ws + off;
        off += (bytes + 255) & ~(size_t)255;
        return p;
    };

    // ---- fixed residents (~5.8 MB) ----
    float* net = (float*)alloc((size_t)M_ROWS * 4);
    float* c1 = (float*)alloc((size_t)M_ROWS * 4);
    _Float16* W0F = (_Float16*)alloc((size_t)IN_DIM * H_DIM * 2);
    _Float16* W1F = (_Float16*)alloc((size_t)H_DIM * H_DIM * 2);
    _Float16* W2F = (_Float16*)alloc((size_t)H_DIM * H_DIM * 2);
    _Float16* W3h = (_Float16*)alloc((size_t)H_DIM * 2);

    // ---- chunk rows: multiple of 1024 (XCD swizzle path) ----
    const size_t per_row = 512 + 2048 + 2048;
    size_t avail = (ws_size > off + 65536) ? (ws_size - off - 65536) : 0;
    long Rl = (long)(avail / per_row);
    Rl = (Rl / 1024) * 1024;
    if (Rl < 128) Rl = 128;
    if (Rl > M_ROWS) Rl = M_ROWS;
    const int R = (int)Rl;

    _Float16* Xc = (_Float16*)alloc((size_t)R * IN_DIM * 2);
    _Float16* HAc = (_Float16*)alloc((size_t)R * H_DIM * 2);
    _Float16* HBc = (_Float16*)alloc((size_t)R * H_DIM * 2);

    // ---- weights once per call (fragment-major) ----
    wt_frag_kernel<<<(IN_DIM / 32) * (H_DIM / 64), 256, 0, stream>>>(W0, W0F,
                                                                     IN_DIM, H_DIM);
    wt_frag_kernel<<<(H_DIM / 32) * (H_DIM / 64), 256, 0, stream>>>(W1, W1F,
                                                                    H_DIM, H_DIM);
    wt_frag_kernel<<<(H_DIM / 32) * (H_DIM / 64), 256, 0, stream>>>(W2, W2F,
                                                                    H_DIM, H_DIM);
    wt_vec_kernel<<<4, 256, 0, stream>>>(W3, W3h, H_DIM);
    zero_kernel<<<M_ROWS / 256, 256, 0, stream>>>(net, M_ROWS);

    // ---- chunked MLP pipeline ----
    for (int r0 = 0; r0 < M_ROWS; r0 += R) {
        int Mc = M_ROWS - r0;
        if (Mc > R) Mc = R;
        int nElem = Mc * F_DIM;
        int pgrid = (nElem + 256 * 8 - 1) / (256 * 8);
        if (pgrid > 2048) pgrid = 2048;
        prep_u_kernel<<<pgrid, 256, 0, stream>>>(u + (size_t)r0 * F_DIM, Xc,
                                                 c1 + r0, nElem);

        dim3 blk(256);
        dim3 grd((Mc / 128) * (H_DIM / 128));  // 1D, swizzled in-kernel
        gemm_f16<<<grd, blk, 0, stream>>>(Xc, W0F, b0, HAc, Mc, H_DIM, IN_DIM);
        gemm_f16<<<grd, blk, 0, stream>>>(HAc, W1F, b1, HBc, Mc, H_DIM, H_DIM);
        gemm_dot<<<grd, blk, 0, stream>>>(HBc, W2F, b2, W3h, net + r0, Mc,
                                          H_DIM, H_DIM);
    }

    // ---- scan ----
    scan_kernel<<<1, 256, 0, stream>>>(net, c1, u, pa, pb, b3, out);
}